// Round 2
// baseline (13388.924 us; speedup 1.0000x reference)
//
#include <hip/hip_runtime.h>
#include <math.h>

typedef __bf16 bf;
typedef __attribute__((ext_vector_type(2))) __bf16 bfv2;
typedef __attribute__((ext_vector_type(4))) __bf16 bfv4;
typedef __attribute__((ext_vector_type(8))) __bf16 bfv8;
typedef __attribute__((ext_vector_type(4))) float f32x4;

__device__ __forceinline__ void gload16(const void* g, void* l) {
  __builtin_amdgcn_global_load_lds((const __attribute__((address_space(1))) void*)g,
                                   (__attribute__((address_space(3))) void*)l, 16, 0, 0);
}

// ---------------- GEMM: C[M,N] = A[M,K] * Bt[N,K]^T  (bf16 in, f32 accum) ----------------
// 128x128 tile, BK=32, 4 waves, 16x16x32 MFMA.
// Generalized K addressing: elem(k) at (k>>9)*lK + (k&511)  (normal GEMM: lK=512 -> ==k).
// MASK: causal im2col on A (i=k>>9 valid iff (row&15)>=i), masked lanes read zero page.
// ACC: C += result (f32 path only).
template<int TWO,int BIAS,int OF32,int OB16,int MASK,int ACC>
__global__ __launch_bounds__(256) void gemm_k(
    const bf* __restrict__ A, long lda, long lKa, long sAz,
    const bf* __restrict__ Bt, long ldb, long lKb, long sBz,
    const bf* __restrict__ A2, long lda2, const bf* __restrict__ B2, long ldb2, int K2,
    float* __restrict__ C, long ldc, long sCz,
    bf* __restrict__ Cb, long ldcb, long sCbz,
    const float* __restrict__ bias, int K, const bf* __restrict__ zpg)
{
  __shared__ bf lsA[4096], lsB[4096];
  const int t = threadIdx.x, z = blockIdx.z;
  const long m0 = (long)blockIdx.x * 128, n0 = (long)blockIdx.y * 128;
  const bf* Ap = A + (long)z * sAz;
  const bf* Bp = Bt + (long)z * sBz;
  long la = lda, lb = ldb; int KK = K;
  const int w = t >> 6, l = t & 63;
  const int wm = (w >> 1) * 64, wn = (w & 1) * 64;
  const int lr = l & 15, lk = (l >> 4) * 8;
  const int r0 = t >> 2, ko = (t & 3) * 8;
  f32x4 acc[4][4];
  #pragma unroll
  for (int i = 0; i < 4; i++)
    #pragma unroll
    for (int j = 0; j < 4; j++) acc[i][j] = (f32x4){0.f, 0.f, 0.f, 0.f};

  for (int src = 0; ; ++src) {
    for (int k0 = 0; k0 < KK; k0 += 32) {
      const int kk = k0 + ko;
      const long ka = (long)(kk >> 9) * lKa + (kk & 511);
      const long kb = (long)(kk >> 9) * lKb + (kk & 511);
      const bf* ga  = Ap + (m0 + r0) * la + ka;
      const bf* ga2 = ga + 64 * la;
      if (MASK) {
        if (!((int)((m0 + r0) & 15) >= (kk >> 9))) { ga = zpg; ga2 = zpg; }
      }
      const bf* gb = Bp + (n0 + r0) * lb + kb;
      gload16(ga,           &lsA[t * 8]);
      gload16(ga2,          &lsA[2048 + t * 8]);
      gload16(gb,           &lsB[t * 8]);
      gload16(gb + 64 * lb, &lsB[2048 + t * 8]);
      __syncthreads();
      bfv8 av[4], bv[4];
      #pragma unroll
      for (int i = 0; i < 4; i++) av[i] = *(const bfv8*)&lsA[(wm + i * 16 + lr) * 32 + lk];
      #pragma unroll
      for (int i = 0; i < 4; i++) bv[i] = *(const bfv8*)&lsB[(wn + i * 16 + lr) * 32 + lk];
      #pragma unroll
      for (int i = 0; i < 4; i++)
        #pragma unroll
        for (int j = 0; j < 4; j++)
          acc[i][j] = __builtin_amdgcn_mfma_f32_16x16x32_bf16(av[i], bv[j], acc[i][j], 0, 0, 0);
      __syncthreads();
    }
    if (!TWO || src) break;
    Ap = A2; Bp = B2; la = lda2; lb = ldb2; KK = K2;
  }
  const int orow = (l >> 4) * 4, ocol = lr;
  #pragma unroll
  for (int i = 0; i < 4; i++)
    #pragma unroll
    for (int j = 0; j < 4; j++) {
      long col = n0 + wn + j * 16 + ocol;
      float bb = BIAS ? bias[col] : 0.f;
      #pragma unroll
      for (int r = 0; r < 4; r++) {
        long row = m0 + wm + i * 16 + orow + r;
        float v = acc[i][j][r] + bb;
        if (OF32) {
          long idx = (long)z * sCz + row * ldc + col;
          if (ACC) v += C[idx];
          C[idx] = v;
        }
        if (OB16) Cb[(long)z * sCbz + row * ldcb + col] = (bf)v;
      }
    }
}

template<int TWO,int BIAS,int OF32,int OB16,int MASK,int ACC>
static inline void launch_gemm(hipStream_t st, int M, int N, int Z,
    const void* A, long lda, long lKa, long sAz,
    const void* B, long ldb, long lKb, long sBz,
    const void* A2, long lda2, const void* B2, long ldb2, int K2,
    void* C, long ldc, long sCz, void* Cb, long ldcb, long sCbz,
    const void* bias, int K, const void* zpg) {
  dim3 g(M / 128, N / 128, Z);
  gemm_k<TWO,BIAS,OF32,OB16,MASK,ACC><<<g, 256, 0, st>>>(
      (const bf*)A, lda, lKa, sAz, (const bf*)B, ldb, lKb, sBz,
      (const bf*)A2, lda2, (const bf*)B2, ldb2, K2,
      (float*)C, ldc, sCz, (bf*)Cb, ldcb, sCbz, (const float*)bias, K, (const bf*)zpg);
}

// ---------------- small kernels ----------------

// tiled transpose-cast: out[z][r][c] = (TO) in[z*inz + c*ldin + r]
template<typename TI, typename TO>
__global__ __launch_bounds__(256) void k_trt(const TI* __restrict__ in, TO* __restrict__ out,
                                             long ldin, long inz, long ldout, long outz) {
  __shared__ float tile[64][65];
  int z = blockIdx.z;
  int c0 = blockIdx.x * 64, r0 = blockIdx.y * 64;
  int tx = threadIdx.x & 63, ty = threadIdx.x >> 6;
  #pragma unroll
  for (int i = ty; i < 64; i += 4) tile[i][tx] = (float)in[(long)z * inz + (long)(c0 + i) * ldin + r0 + tx];
  __syncthreads();
  #pragma unroll
  for (int i = ty; i < 64; i += 4) out[(long)z * outz + (long)(r0 + i) * ldout + c0 + tx] = (TO)tile[tx][i];
}

// strided gather-cast: out[z*outz + id] = (r<RIN)? in[z*inz + c*S1 + r*S2] : 0  (r=id/CO, c=id%CO)
__global__ void k_gath(const float* __restrict__ in, bf* __restrict__ out,
                       long S1, long S2, long inz, long outz, long n, int CO, int RIN) {
  long id = (long)blockIdx.x * 256 + threadIdx.x;
  if (id >= n) return;
  int z = blockIdx.y;
  long r = id / CO, c = id % CO;
  float v = (r < RIN) ? in[(long)z * inz + c * S1 + r * S2] : 0.f;
  out[(long)z * outz + id] = (bf)v;
}

// MuT[z][(i,o)][d] = m_u[z][o][d][i]
__global__ void k_mut(const float* __restrict__ mu, bf* __restrict__ out) {
  long id = (long)blockIdx.x * 256 + threadIdx.x;  // < 786432
  int z = blockIdx.y;
  long r = id >> 9; int d = (int)(id & 511);
  int i = (int)(r >> 9), o = (int)(r & 511);
  out[(long)z * 786432 + id] = (bf)mu[(long)z * 786432 + (long)o * 1536 + d * 3 + i];
}

__global__ void k_ident(bf* __restrict__ g) {
  long id = (long)blockIdx.x * 256 + threadIdx.x;  // < 262144
  int i = (int)(id >> 9), j = (int)(id & 511);
  g[id] = (bf)((i == j) ? 1.f : 0.f);
}

// T = [[P16 | P15*B],[P15 | P14*B]]  (Z=1)
__global__ void k_asmT(const bf* __restrict__ pst, const bf* __restrict__ x1,
                       const bf* __restrict__ x2, bf* __restrict__ T) {
  long id = (long)blockIdx.x * 256 + threadIdx.x;  // < 1048576
  int p = (int)(id >> 10), q = (int)(id & 1023);
  bf v;
  if (p < 512) v = (q < 512) ? pst[16L * 262144 + (long)p * 512 + q] : x1[(long)p * 512 + (q - 512)];
  else         v = (q < 512) ? pst[15L * 262144 + (long)(p - 512) * 512 + q] : x2[(long)(p - 512) * 512 + (q - 512)];
  T[id] = v;
}

// forward DFT table rows n=2f+c: c0=cos(2pi f s/2048), c1=-sin (f<=1024, rest 0)
__global__ void k_dftfwd(bf* __restrict__ out) {
  int s = blockIdx.x * 256 + threadIdx.x;
  int n = blockIdx.y;
  if (s >= 1024) return;
  int f = n >> 1;
  float v = 0.f;
  if (f <= 1024) {
    int m = (f * s) & 2047; if (m >= 1024) m -= 2048;
    float ang = (float)m * 0.0030679615757712823f;
    float sn, cs; sincosf(ang, &sn, &cs);
    v = (n & 1) ? -sn : cs;
  }
  out[(long)n * 1024 + s] = (bf)v;
}

// inverse cos/sin table: CS[t][2f+0]=cos(2pi f t/2048), [2f+1]=-sin
__global__ void k_cst(bf* __restrict__ cs) {
  int f = blockIdx.x * 256 + threadIdx.x; if (f >= 1088) return;
  int t = blockIdx.y;
  int m = (f * t) & 2047; if (m >= 1024) m -= 2048;
  float ang = (float)m * 0.0030679615757712823f;
  float sn, c; sincosf(ang, &sn, &c);
  bfv2 o; o[0] = (bf)c; o[1] = (bf)(-sn);
  *(bfv2*)&cs[(long)t * 2176 + 2 * f] = o;
}

// fold eigval^0.25 * w_f / n into Vhat
__global__ void k_vfold(const float* __restrict__ vh, const float* __restrict__ ev,
                        float* __restrict__ vre, float* __restrict__ vim) {
  int f = blockIdx.x * 256 + threadIdx.x; if (f >= 1088) return;
  int k = blockIdx.y;
  float a = (f == 0 || f == 1024) ? (1.f / 2048.f) : (f < 1024 ? 2.f / 2048.f : 0.f);
  float sv = powf(ev[k], 0.25f) * a;
  float re = 0.f, im = 0.f;
  if (f <= 1024) { re = vh[(long)k * 2176 + 2 * f]; im = vh[(long)k * 2176 + 2 * f + 1]; }
  vre[k * 1088 + f] = sv * re; vim[k * 1088 + f] = sv * im;
}

// complex multiply U * Vk -> PQI rows [b][kk][d], cols 2f+c  (bf16)
__global__ void k_cmul(const bf* __restrict__ UB, const float* __restrict__ vre,
                       const float* __restrict__ vim, bf* __restrict__ pqi, int nk, int kc) {
  long id = (long)blockIdx.x * 256 + threadIdx.x;
  long tot = (long)nk * 4 * 512 * 1088;
  if (id >= tot) return;
  int f = (int)(id % 1088); long r = id / 1088;
  int d = (int)(r & 511); long q = r >> 9;
  int kk = (int)(q % nk); int b = (int)(q / nk);
  int kg = kc * nk + kk;
  bfv2 u = *(const bfv2*)&UB[((long)b * 512 + d) * 2176 + 2 * f];
  float ur = (float)u[0], ui = (float)u[1];
  float vr = vre[kg * 1088 + f], vi = vim[kg * 1088 + f];
  bfv2 o; o[0] = (bf)(ur * vr - ui * vi); o[1] = (bf)(ur * vi + ui * vr);
  *(bfv2*)&pqi[r * 2176 + 2 * f] = o;
}

__global__ __launch_bounds__(256) void k_ln(const float* __restrict__ x, const float* __restrict__ sc,
                                            const float* __restrict__ bi, float* __restrict__ h, bf* __restrict__ hb) {
  __shared__ float red[8];
  long row = blockIdx.x;
  const float* xr = x + row * 512;
  int t = threadIdx.x;
  float a = xr[t], b2 = xr[t + 256];
  float s = a + b2;
  #pragma unroll
  for (int o = 32; o; o >>= 1) s += __shfl_down(s, o, 64);
  if ((t & 63) == 0) red[t >> 6] = s;
  __syncthreads();
  float mu = (red[0] + red[1] + red[2] + red[3]) * (1.f / 512.f);
  __syncthreads();
  float c1 = a - mu, c2 = b2 - mu;
  float qq = c1 * c1 + c2 * c2;
  #pragma unroll
  for (int o = 32; o; o >>= 1) qq += __shfl_down(qq, o, 64);
  if ((t & 63) == 0) red[t >> 6] = qq;
  __syncthreads();
  float var = (red[0] + red[1] + red[2] + red[3]) * (1.f / 512.f);
  float rs = rsqrtf(var + 1e-5f);
  float o1 = c1 * rs * sc[t] + bi[t];
  float o2 = c2 * rs * sc[t + 256] + bi[t + 256];
  h[row * 512 + t] = o1; h[row * 512 + t + 256] = o2;
  hb[row * 512 + t] = (bf)o1; hb[row * 512 + t + 256] = (bf)o2;
}

// DELTAB = bf16(DELTA + shifted AR terms)
__global__ void k_deltas3(const float* __restrict__ delta, const bf* __restrict__ callb,
                          bf* __restrict__ db) {
  long id = (long)blockIdx.x * 256 + threadIdx.x;  // < 2097152
  int o = (int)(id & 511); long row = id >> 9; int tt = (int)(row & 1023);
  float v = delta[id];
  #pragma unroll
  for (int i = 0; i < 3; ++i)
    if (tt >= i) v += (float)callb[(row - i) * 1536 + i * 512 + o];
  db[id] = (bf)v;
}

// sequential chunk-state scan: s_{c+1} = T s_c + e_c ; 32 WGs, global spin barrier
__global__ __launch_bounds__(128) void k_scan(const bf* __restrict__ T, const float* __restrict__ yloc,
                                              float* __restrict__ ss, bf* __restrict__ ssb, int* __restrict__ bar) {
  const int t = threadIdx.x;
  const int b = t >> 5, p = t & 31;
  const int prow = blockIdx.x * 32 + p;
  const long tbase = (long)prow * 1024;
  float cur = 0.f;
  __shared__ int ls_sh;
  if (t == 0) ls_sh = 0;
  __syncthreads();
  for (int c = 0; c < 64; ++c) {
    long so = ((long)b * 64 + c) * 1024 + prow;
    ss[so] = cur; ssb[so] = (bf)cur;
    __syncthreads();
    if (t == 0) {
      int s = ls_sh ^ 1; ls_sh = s;
      __threadfence();
      int old = __hip_atomic_fetch_add(bar, 1, __ATOMIC_ACQ_REL, __HIP_MEMORY_SCOPE_AGENT);
      if (old == 31) {
        __hip_atomic_store(bar, 0, __ATOMIC_RELAXED, __HIP_MEMORY_SCOPE_AGENT);
        __hip_atomic_store(bar + 1, s, __ATOMIC_RELEASE, __HIP_MEMORY_SCOPE_AGENT);
      } else {
        while (__hip_atomic_load(bar + 1, __ATOMIC_RELAXED, __HIP_MEMORY_SCOPE_AGENT) != s)
          __builtin_amdgcn_s_sleep(8);
        __threadfence();
      }
    }
    __syncthreads();
    if (c == 63) break;
    const float* scp = ss + ((long)b * 64 + c) * 1024;
    float acc = 0.f;
    #pragma unroll 4
    for (int q = 0; q < 1024; q += 8) {
      bfv8 tv = *(const bfv8*)(T + tbase + q);
      const float4* sp = (const float4*)(scp + q);
      float4 s0 = sp[0], s1 = sp[1];
      acc += (float)tv[0] * s0.x + (float)tv[1] * s0.y + (float)tv[2] * s0.z + (float)tv[3] * s0.w
           + (float)tv[4] * s1.x + (float)tv[5] * s1.y + (float)tv[6] * s1.z + (float)tv[7] * s1.w;
    }
    int tq = c * 16 + ((prow < 512) ? 15 : 14);
    int pp = prow & 511;
    cur = acc + yloc[((long)b * 1024 + tq) * 512 + pp];
  }
}

// y = yloc + P_{j+1} u + P_j Bv ; out = bf16(gelu(y))
__global__ void k_combgelu(const float* __restrict__ yloc, const bf* __restrict__ o1,
                           const bf* __restrict__ o2, bf* __restrict__ yg) {
  long id = (long)blockIdx.x * 256 + threadIdx.x;  // < 2097152
  int o = (int)(id & 511); long row = id >> 9;
  int b = (int)(row >> 10), tt = (int)(row & 1023);
  int c = tt >> 4, j = tt & 15;
  long wv = ((long)(j * 512 + o)) * 256 + b * 64 + c;
  float v = yloc[id] + (float)o1[wv] + (float)o2[wv];
  yg[id] = (bf)(0.5f * v * (1.f + erff(v * 0.70710678118654752f)));
}

__global__ void k_glures(const bf* __restrict__ g, float* __restrict__ x) {
  long id = (long)blockIdx.x * 256 + threadIdx.x;  // < 2097152
  int o = (int)(id & 511); long row = id >> 9;
  float a = (float)g[row * 1024 + o], bb = (float)g[row * 1024 + 512 + o];
  x[id] = x[id] + a / (1.f + expf(-bb));
}

__global__ void k_cast(const float* __restrict__ in, bf* __restrict__ out, long n4) {
  long id = (long)blockIdx.x * 256 + threadIdx.x;
  if (id >= n4) return;
  float4 v = *(const float4*)(in + id * 4);
  bfv4 o; o[0] = (bf)v.x; o[1] = (bf)v.y; o[2] = (bf)v.z; o[3] = (bf)v.w;
  *(bfv4*)(out + id * 4) = o;
}

__global__ void k_fill(float* p, long n, float v) {
  long id = (long)blockIdx.x * 256 + threadIdx.x;
  if (id < n) p[id] = v;
}

// ---------------- workspace layout ----------------
struct Lay {
  long BAR, ZPG, DFTF, CST, VHF, VRE, VIM, EVT, EMBT, PROJT, MUT, W1T,
       MYA, MYB, MYBT, X, GSTL, PSTL, TSTL, X1B, X2B, MPHITL, HB,
       R1, R2, R3, R4, R5, SST, SSTB, BVB, need;
};
static Lay mkLay(int nk) {
  long o = 0; Lay L;
  auto al = [&](long sz) { long r = o; o += (sz + 255) & ~255L; return r; };
  auto mx = [](long a, long b) { return a > b ? a : b; };
  L.BAR = al(2048); L.ZPG = al(2048);
  L.DFTF = al(2176L * 1024 * 2);
  L.CST  = al(1024L * 2176 * 2);
  L.VHF  = al(128L * 2176 * 4);
  L.VRE  = al(24L * 1088 * 4);
  L.VIM  = al(24L * 1088 * 4);
  L.EVT  = al(128L * 1024 * 2);
  L.EMBT = al(512L * 512 * 2);
  L.PROJT= al(512L * 512 * 2);
  L.MUT  = al(4L * 1536 * 512 * 2);
  L.W1T  = al(4L * 1024 * 512 * 2);
  L.MYA  = al(4L * 512 * 512 * 2);
  L.MYB  = al(4L * 512 * 512 * 2);
  L.MYBT = al(4L * 512 * 512 * 2);
  L.X    = al(4096L * 512 * 4);
  L.GSTL = al(17L * 512 * 512 * 2);
  L.PSTL = al(17L * 512 * 512 * 2);
  L.TSTL = al(1024L * 1024 * 2);
  L.X1B  = al(512L * 512 * 2);
  L.X2B  = al(512L * 512 * 2);
  L.MPHITL = al(512L * 12288 * 2);
  L.HB   = al(4096L * 512 * 2);
  L.R1 = al(mx(4096L * 512 * 4, (long)nk * 2048 * 2176 * 2));   // H f32 | PQI
  L.R2 = al(mx((long)nk * 4096 * 512 * 2, 4096L * 512 * 2));     // XTC | HTB | DELTAB
  L.R3 = al(2048L * 2176 * 2);                                   // UB | YLOC
  L.R4 = al(4096L * 512 * 4);                                    // DELTA | YGB
  L.R5 = al(4096L * 1536 * 2);                                   // CALLB | OUT1+OUT2 | G
  L.SST  = al(4L * 64 * 1024 * 4);
  L.SSTB = al(4L * 64 * 1024 * 2);
  L.BVB  = al(256L * 512 * 2);
  L.need = o;
  return L;
}

extern "C" void kernel_launch(void* const* d_in, const int* in_sizes, int n_in,
                              void* d_out, int out_size, void* d_ws, size_t ws_size,
                              hipStream_t stream) {
  int nk = 3;
  Lay L = mkLay(nk);
  while (nk > 1 && L.need > (long)ws_size) { --nk; L = mkLay(nk); }
  if (L.need > (long)ws_size) {  // diagnostic: absmax ~= 1e6 + ws_MB
    k_fill<<<8192, 256, 0, stream>>>((float*)d_out, 2097152, 1.0e6f + (float)(ws_size >> 20));
    return;
  }
  const float* inp  = (const float*)d_in[0];
  const float* embw = (const float*)d_in[1];
  const float* embb = (const float*)d_in[2];
  const float* lns  = (const float*)d_in[3];
  const float* lnb  = (const float*)d_in[4];
  const float* m_y  = (const float*)d_in[5];
  const float* m_u  = (const float*)d_in[6];
  const float* mphi = (const float*)d_in[7];
  const float* w1   = (const float*)d_in[8];
  const float* b1   = (const float*)d_in[9];
  const float* pw   = (const float*)d_in[10];
  const float* pb   = (const float*)d_in[11];
  const float* evals = (const float*)d_in[12];
  const float* evecs = (const float*)d_in[13];

  char* w = (char*)d_ws;
  int*   BARi  = (int*)(w + L.BAR);
  bf*    ZPG   = (bf*)(w + L.ZPG);
  bf*    DFTF  = (bf*)(w + L.DFTF);
  bf*    CST   = (bf*)(w + L.CST);
  float* VHF   = (float*)(w + L.VHF);
  float* VRE   = (float*)(w + L.VRE);
  float* VIM   = (float*)(w + L.VIM);
  bf*    EVT   = (bf*)(w + L.EVT);
  bf*    EMBT  = (bf*)(w + L.EMBT);
  bf*    PROJT = (bf*)(w + L.PROJT);
  bf*    MUT   = (bf*)(w + L.MUT);
  bf*    W1T   = (bf*)(w + L.W1T);
  bf*    MYA   = (bf*)(w + L.MYA);
  bf*    MYB   = (bf*)(w + L.MYB);
  bf*    MYBT  = (bf*)(w + L.MYBT);
  float* X     = (float*)(w + L.X);
  bf*    GSTL  = (bf*)(w + L.GSTL);
  bf*    PSTL  = (bf*)(w + L.PSTL);
  bf*    TSTL  = (bf*)(w + L.TSTL);
  bf*    X1B   = (bf*)(w + L.X1B);
  bf*    X2B   = (bf*)(w + L.X2B);
  bf*    MPHITL= (bf*)(w + L.MPHITL);
  bf*    HB    = (bf*)(w + L.HB);
  float* H     = (float*)(w + L.R1);     // R1: H | PQI
  bf*    PQI   = (bf*)(w + L.R1);
  bf*    HTB   = (bf*)(w + L.R2);        // R2: HTB | XTC | DELTAB
  bf*    XTC   = (bf*)(w + L.R2);
  bf*    DELTAB= (bf*)(w + L.R2);
  bf*    UB    = (bf*)(w + L.R3);        // R3: UB | YLOC
  float* YLOC  = (float*)(w + L.R3);
  float* DELTA = (float*)(w + L.R4);     // R4: DELTA | YGB
  bf*    YGB   = (bf*)(w + L.R4);
  bf*    CALLB = (bf*)(w + L.R5);        // R5: CALLB | OUT1,OUT2 | G
  bf*    OUT1  = (bf*)(w + L.R5);
  bf*    OUT2  = (bf*)(w + L.R5 + 4194304);
  bf*    G     = (bf*)(w + L.R5);
  float* SST   = (float*)(w + L.SST);
  bf*    SSTB  = (bf*)(w + L.SSTB);
  bf*    BVB   = (bf*)(w + L.BVB);
  bf*    INB   = HB;
  hipStream_t st = stream;

  hipMemsetAsync(w, 0, 4096, st);  // BAR + ZPG

  // ---- one-time tables / weight prep ----
  k_gath<<<dim3(512, 1), 256, 0, st>>>(evecs, EVT, 24, 1, 0, 0, 131072, 1024, 24);
  k_dftfwd<<<dim3(4, 2176), 256, 0, st>>>(DFTF);
  launch_gemm<0,0,1,0,0,0>(st, 128, 2176, 1, EVT, 1024, 512, 0, DFTF, 1024, 512, 0,
      nullptr, 0, nullptr, 0, 0, VHF, 2176, 0, nullptr, 0, 0, nullptr, 1024, ZPG);
  k_vfold<<<dim3(5, 24), 256, 0, st>>>(VHF, evals, VRE, VIM);
  k_cst<<<dim3(5, 1024), 256, 0, st>>>(CST);
  k_trt<float, bf><<<dim3(8, 8, 1), 256, 0, st>>>(embw, EMBT, 512, 0, 512, 0);
  k_trt<float, bf><<<dim3(8, 8, 1), 256, 0, st>>>(pw, PROJT, 512, 0, 512, 0);
  k_mut<<<dim3(3072, 4), 256, 0, st>>>(m_u, MUT);
  k_trt<float, bf><<<dim3(8, 16, 4), 256, 0, st>>>(w1, W1T, 1024, 524288, 512, 524288);
  k_gath<<<dim3(1024, 4), 256, 0, st>>>(m_y, MYA, 1, 1024, 524288, 262144, 262144, 512, 512);
  k_gath<<<dim3(1024, 4), 256, 0, st>>>(m_y + 512, MYB, 1, 1024, 524288, 262144, 262144, 512, 512);
  k_trt<float, bf><<<dim3(8, 8, 4), 256, 0, st>>>(m_y + 512, MYBT, 1024, 524288, 512, 262144);
  // embedding
  k_cast<<<2048, 256, 0, st>>>(inp, INB, 524288);
  launch_gemm<0,1,1,0,0,0>(st, 4096, 512, 1, INB, 512, 512, 0, EMBT, 512, 512, 0,
      nullptr, 0, nullptr, 0, 0, X, 512, 0, nullptr, 0, 0, embb, 512, ZPG);

  const int nchunk = 24 / nk;
  for (int l = 0; l < 4; ++l) {
    const bf* MYAl = MYA + (long)l * 262144;
    const bf* MYBl = MYB + (long)l * 262144;
    // --- per-layer state-space prep: G powers, P = G^T, T, m_phi^T ---
    k_ident<<<dim3(1024, 1), 256, 0, st>>>(GSTL);
    k_trt<float, bf><<<dim3(8, 8, 1), 256, 0, st>>>(m_y + (long)l * 524288, GSTL + 262144, 1024, 0, 512, 0);
    for (int i = 2; i <= 16; ++i)
      launch_gemm<1,0,0,1,0,0>(st, 512, 512, 1,
          GSTL + (long)(i - 1) * 262144, 512, 512, 0, MYAl, 512, 512, 0,
          GSTL + (long)(i - 2) * 262144, 512, MYBl, 512, 512,
          nullptr, 0, 0, GSTL + (long)i * 262144, 512, 0, nullptr, 512, ZPG);
    k_trt<bf, bf><<<dim3(8, 8, 17), 256, 0, st>>>(GSTL, PSTL, 512, 262144, 512, 262144);
    launch_gemm<0,0,0,1,0,0>(st, 512, 512, 1, PSTL + 15L * 262144, 512, 512, 0,
        MYBT + (long)l * 262144, 512, 512, 0, nullptr, 0, nullptr, 0, 0,
        nullptr, 0, 0, X1B, 512, 0, nullptr, 512, ZPG);
    launch_gemm<0,0,0,1,0,0>(st, 512, 512, 1, PSTL + 14L * 262144, 512, 512, 0,
        MYBT + (long)l * 262144, 512, 512, 0, nullptr, 0, nullptr, 0, 0,
        nullptr, 0, 0, X2B, 512, 0, nullptr, 512, ZPG);
    k_asmT<<<4096, 256, 0, st>>>(PSTL, X1B, X2B, TSTL);
    k_trt<float, bf><<<dim3(192, 8, 1), 256, 0, st>>>(mphi + (long)l * 6291456, MPHITL, 512, 0, 12288, 0);

    // --- LN, forward DFT ---
    k_ln<<<4096, 256, 0, st>>>(X, lns + l * 512, lnb + l * 512, H, HB);
    k_trt<float, bf><<<dim3(16, 8, 4), 256, 0, st>>>(H, HTB, 512, 524288, 1024, 524288);
    launch_gemm<0,0,0,1,0,0>(st, 2048, 2176, 1, HTB, 1024, 512, 0, DFTF, 1024, 512, 0,
        nullptr, 0, nullptr, 0, 0, nullptr, 0, 0, UB, 2176, 0, nullptr, 1024, ZPG);

    // --- spectral: per k-chunk cmul -> inverse-DFT GEMM -> accumulate into DELTA ---
    for (int kc = 0; kc < nchunk; ++kc) {
      long tot = (long)nk * 4 * 512 * 1088;
      k_cmul<<<dim3((unsigned)((tot + 255) / 256)), 256, 0, st>>>(UB, VRE, VIM, PQI, nk, kc);
      launch_gemm<0,0,0,1,0,0>(st, 1024, nk * 512, 4, CST, 2176, 512, 0,
          PQI, 2176, 512, (long)nk * 512 * 2176, nullptr, 0, nullptr, 0, 0,
          nullptr, 0, 0, XTC, (long)nk * 512, (long)1024 * nk * 512, nullptr, 2176, ZPG);
      if (kc == 0)
        launch_gemm<0,0,1,0,0,0>(st, 4096, 512, 1, XTC, (long)nk * 512, 512, 0,
            MPHITL + (long)kc * nk * 512, 12288, 512, 0, nullptr, 0, nullptr, 0, 0,
            DELTA, 512, 0, nullptr, 0, 0, nullptr, nk * 512, ZPG);
      else
        launch_gemm<0,0,1,0,0,1>(st, 4096, 512, 1, XTC, (long)nk * 512, 512, 0,
            MPHITL + (long)kc * nk * 512, 12288, 512, 0, nullptr, 0, nullptr, 0, 0,
            DELTA, 512, 0, nullptr, 0, 0, nullptr, nk * 512, ZPG);
    }

    // --- AR terms, deltas ---
    launch_gemm<0,0,0,1,0,0>(st, 4096, 1536, 1, HB, 512, 512, 0, MUT + (long)l * 786432, 512, 512, 0,
        nullptr, 0, nullptr, 0, 0, nullptr, 0, 0, CALLB, 1536, 0, nullptr, 512, ZPG);
    k_deltas3<<<8192, 256, 0, st>>>(DELTA, CALLB, DELTAB);

    // --- local solutions (implicit causal im2col A, block-strided P as B) ---
    launch_gemm<0,0,1,0,1,0>(st, 4096, 512, 1, DELTAB, 512, -512, 0,
        PSTL, 512, 262144, 0, nullptr, 0, nullptr, 0, 0,
        YLOC, 512, 0, nullptr, 0, 0, nullptr, 8192, ZPG);

    // --- chunk-state scan + homogeneous completion ---
    k_scan<<<32, 128, 0, st>>>(TSTL, YLOC, SST, SSTB, BARi + l * 16);
    launch_gemm<0,0,0,1,0,0>(st, 256, 512, 1, SSTB + 512, 1024, 512, 0, MYBl, 512, 512, 0,
        nullptr, 0, nullptr, 0, 0, nullptr, 0, 0, BVB, 512, 0, nullptr, 512, ZPG);
    launch_gemm<0,0,0,1,0,0>(st, 8192, 256, 1, PSTL + 262144, 512, 512, 0, SSTB, 1024, 512, 0,
        nullptr, 0, nullptr, 0, 0, nullptr, 0, 0, OUT1, 256, 0, nullptr, 512, ZPG);
    launch_gemm<0,0,0,1,0,0>(st, 8192, 256, 1, PSTL, 512, 512, 0, BVB, 512, 512, 0,
        nullptr, 0, nullptr, 0, 0, nullptr, 0, 0, OUT2, 256, 0, nullptr, 512, ZPG);
    k_combgelu<<<8192, 256, 0, st>>>(YLOC, OUT1, OUT2, YGB);

    // --- MLP (GLU) + residual ---
    launch_gemm<0,1,0,1,0,0>(st, 4096, 1024, 1, YGB, 512, 512, 0, W1T + (long)l * 524288, 512, 512, 0,
        nullptr, 0, nullptr, 0, 0, nullptr, 0, 0, G, 1024, 0, b1 + l * 1024, 512, ZPG);
    k_glures<<<8192, 256, 0, st>>>(G, X);
  }

  // ---- output projection ----
  k_cast<<<2048, 256, 0, st>>>(X, INB, 524288);
  launch_gemm<0,1,1,0,0,0>(st, 4096, 512, 1, INB, 512, 512, 0, PROJT, 512, 512, 0,
      nullptr, 0, nullptr, 0, 0, (float*)d_out, 512, 0, nullptr, 0, 0, pb, 512, ZPG);
}

// Round 3
// 5186.662 us; speedup vs baseline: 2.5814x; 2.5814x over previous
//
#include <hip/hip_runtime.h>
#include <math.h>

typedef __bf16 bf;
typedef __attribute__((ext_vector_type(4))) __bf16 bfv4;
typedef __attribute__((ext_vector_type(8))) __bf16 bfv8;
typedef __attribute__((ext_vector_type(4))) float f32x4;

__device__ __forceinline__ void gload16(const void* g, void* l) {
  __builtin_amdgcn_global_load_lds((const __attribute__((address_space(1))) void*)g,
                                   (__attribute__((address_space(3))) void*)l, 16, 0, 0);
}

// ---------------- GEMM: C[M,N] = A[M,K] * Bt[N,K]^T  (bf16 in, f32 accum) ----------------
// 128x128 tile, BK=32, 4 waves, 16x16x32 MFMA.
// A row addressing: (row>>9)*lMa + (row&511)*la   (standard: lMa = 512*la)
// K addressing (both operands): (k>>9)*lK + (k&511)  (standard: lK = 512)
// Z: A += (z>>zshA)*sAz ; B += (z&zmskB)*sBz ; C/Cb += z*sCz.
// tMASK: causal im2col on A (block i=k>>9 valid iff (row&15)>=i); masked lanes read zero page.
// tACC: C += result (f32 out path).
template<int tB,int tF32,int tB16,int tMASK,int tACC>
__global__ __launch_bounds__(256) void gemm_k(
    const bf* __restrict__ A, long la, long lKa, long lMa, long sAz, int zshA,
    const bf* __restrict__ Bt, long lb, long lKb, long sBz, int zmskB,
    float* __restrict__ C, long ldc, long sCz,
    bf* __restrict__ Cb, long ldcb, long sCbz,
    const float* __restrict__ bias, int K, const bf* __restrict__ zpg)
{
  __shared__ bf lsA[4096], lsB[4096];
  const int t = threadIdx.x, z = blockIdx.z;
  const long m0 = (long)blockIdx.x * 128, n0 = (long)blockIdx.y * 128;
  const bf* Ap = A + (long)(z >> zshA) * sAz;
  const bf* Bp = Bt + (long)(z & zmskB) * sBz;
  const int w = t >> 6, l = t & 63;
  const int wm = (w >> 1) * 64, wn = (w & 1) * 64;
  const int lr = l & 15, lk = (l >> 4) * 8;
  const int r0 = t >> 2, ko = (t & 3) * 8;
  const long rowA1 = m0 + r0, rowA2 = rowA1 + 64;
  const long baseA1 = (rowA1 >> 9) * lMa + (rowA1 & 511) * la;
  const long baseA2 = (rowA2 >> 9) * lMa + (rowA2 & 511) * la;
  const long baseB = (n0 + r0) * lb;
  f32x4 acc[4][4];
  #pragma unroll
  for (int i = 0; i < 4; i++)
    #pragma unroll
    for (int j = 0; j < 4; j++) acc[i][j] = (f32x4){0.f, 0.f, 0.f, 0.f};

  for (int k0 = 0; k0 < K; k0 += 32) {
    const int kk = k0 + ko;
    const long ka = (long)(kk >> 9) * lKa + (kk & 511);
    const long kb = (long)(kk >> 9) * lKb + (kk & 511);
    const bf* ga  = Ap + baseA1 + ka;
    const bf* ga2 = Ap + baseA2 + ka;
    if (tMASK) {
      const int i = kk >> 9;
      if ((int)(rowA1 & 15) < i) { ga = zpg; ga2 = zpg; }
    }
    const bf* gb = Bp + baseB + kb;
    gload16(ga,           &lsA[t * 8]);
    gload16(ga2,          &lsA[2048 + t * 8]);
    gload16(gb,           &lsB[t * 8]);
    gload16(gb + 64 * lb, &lsB[2048 + t * 8]);
    __syncthreads();
    bfv8 av[4], bv[4];
    #pragma unroll
    for (int i = 0; i < 4; i++) av[i] = *(const bfv8*)&lsA[(wm + i * 16 + lr) * 32 + lk];
    #pragma unroll
    for (int i = 0; i < 4; i++) bv[i] = *(const bfv8*)&lsB[(wn + i * 16 + lr) * 32 + lk];
    #pragma unroll
    for (int i = 0; i < 4; i++)
      #pragma unroll
      for (int j = 0; j < 4; j++)
        acc[i][j] = __builtin_amdgcn_mfma_f32_16x16x32_bf16(av[i], bv[j], acc[i][j], 0, 0, 0);
    __syncthreads();
  }
  const int orow = (l >> 4) * 4, ocol = lr;
  #pragma unroll
  for (int i = 0; i < 4; i++)
    #pragma unroll
    for (int j = 0; j < 4; j++) {
      long col = n0 + wn + j * 16 + ocol;
      float bb = tB ? bias[col] : 0.f;
      #pragma unroll
      for (int r = 0; r < 4; r++) {
        long row = m0 + wm + i * 16 + orow + r;
        float v = acc[i][j][r] + bb;
        if (tF32) {
          long idx = (long)z * sCz + row * ldc + col;
          if (tACC) v += C[idx];
          C[idx] = v;
        }
        if (tB16) Cb[(long)z * sCbz + row * ldcb + col] = (bf)v;
      }
    }
}

template<int tB,int tF32,int tB16,int tMASK,int tACC>
static inline void gemm(hipStream_t st, int M, int N, int Z,
    const void* A, long la, long lKa, long lMa, long sAz, int zshA,
    const void* B, long lb, long lKb, long sBz, int zmskB,
    void* C, long ldc, long sCz, void* Cb, long ldcb, long sCbz,
    const void* bias, int K, const void* zpg) {
  dim3 g(M / 128, N / 128, Z);
  gemm_k<tB,tF32,tB16,tMASK,tACC><<<g, 256, 0, st>>>(
      (const bf*)A, la, lKa, lMa, sAz, zshA, (const bf*)B, lb, lKb, sBz, zmskB,
      (float*)C, ldc, sCz, (bf*)Cb, ldcb, sCbz, (const float*)bias, K, (const bf*)zpg);
}

// ---------------- small kernels ----------------

// tiled transpose-cast: out[z][r][c] = (TO) in[z*inz + c*ldin + r]
template<typename TI, typename TO>
__global__ __launch_bounds__(256) void k_trt(const TI* __restrict__ in, TO* __restrict__ out,
                                             long ldin, long inz, long ldout, long outz) {
  __shared__ float tile[64][65];
  int z = blockIdx.z;
  int c0 = blockIdx.x * 64, r0 = blockIdx.y * 64;
  int tx = threadIdx.x & 63, ty = threadIdx.x >> 6;
  #pragma unroll
  for (int i = ty; i < 64; i += 4) tile[i][tx] = (float)in[(long)z * inz + (long)(c0 + i) * ldin + r0 + tx];
  __syncthreads();
  #pragma unroll
  for (int i = ty; i < 64; i += 4) out[(long)z * outz + (long)(r0 + i) * ldout + c0 + tx] = (TO)tile[tx][i];
}

// MuT[(i,o)][d] = m_u_l[o][d][i]
__global__ void k_mut(const float* __restrict__ mul_, bf* __restrict__ out) {
  long id = (long)blockIdx.x * 256 + threadIdx.x;  // < 786432
  long r = id >> 9; int d = (int)(id & 511);
  int i = (int)(r >> 9), o = (int)(r & 511);
  out[id] = (bf)mul_[(long)o * 1536 + d * 3 + i];
}

// CMPOW[0] = I(1024), CMPOW[1] = [[A,B],[I,0]] from m_y layer slice
__global__ void k_buildCM(const float* __restrict__ myl, bf* __restrict__ cmpow) {
  long id = (long)blockIdx.x * 256 + threadIdx.x;  // < 2097152
  int half = (int)(id >> 20);
  int r = (int)(id & 1048575);
  int p = r >> 10, q = r & 1023;
  float v;
  if (half == 0) v = (p == q) ? 1.f : 0.f;
  else if (p < 512) v = myl[(long)p * 1024 + q];
  else v = (q == p - 512) ? 1.f : 0.f;
  cmpow[id] = (bf)v;
}

// Toeplitz filter tables: out[kl][t][s] = (t>=s)? evec[t-s][k0+kl]*evals[k0+kl]^0.25 : 0
__global__ void k_toep(const float* __restrict__ evecs, const float* __restrict__ evals,
                       bf* __restrict__ out, int k0, int nkk) {
  long id = (long)blockIdx.x * 256 + threadIdx.x;
  if (id >= (long)nkk * 1048576) return;
  int kl = (int)(id >> 20);
  int r = (int)(id & 1048575);
  int tt = r >> 10, s = r & 1023;
  int k = k0 + kl;
  float v = 0.f;
  if (tt >= s) v = evecs[(long)(tt - s) * 24 + k] * powf(evals[k], 0.25f);
  out[id] = (bf)v;
}

__global__ __launch_bounds__(256) void k_ln(const float* __restrict__ x, const float* __restrict__ sc,
                                            const float* __restrict__ bi, bf* __restrict__ hb) {
  __shared__ float red[8];
  long row = blockIdx.x;
  const float* xr = x + row * 512;
  int t = threadIdx.x;
  float a = xr[t], b2 = xr[t + 256];
  float s = a + b2;
  #pragma unroll
  for (int o = 32; o; o >>= 1) s += __shfl_down(s, o, 64);
  if ((t & 63) == 0) red[t >> 6] = s;
  __syncthreads();
  float mu = (red[0] + red[1] + red[2] + red[3]) * (1.f / 512.f);
  __syncthreads();
  float c1 = a - mu, c2 = b2 - mu;
  float qq = c1 * c1 + c2 * c2;
  #pragma unroll
  for (int o = 32; o; o >>= 1) qq += __shfl_down(qq, o, 64);
  if ((t & 63) == 0) red[t >> 6] = qq;
  __syncthreads();
  float var = (red[0] + red[1] + red[2] + red[3]) * (1.f / 512.f);
  float rs = rsqrtf(var + 1e-5f);
  hb[row * 512 + t]       = (bf)(c1 * rs * sc[t] + bi[t]);
  hb[row * 512 + t + 256] = (bf)(c2 * rs * sc[t + 256] + bi[t + 256]);
}

// DELTAB = bf16(DELTA + shifted AR terms)
__global__ void k_deltas3(const float* __restrict__ delta, const bf* __restrict__ callb,
                          bf* __restrict__ db) {
  long id = (long)blockIdx.x * 256 + threadIdx.x;  // < 2097152
  int o = (int)(id & 511); long row = id >> 9; int tt = (int)(row & 1023);
  float v = delta[id];
  #pragma unroll
  for (int i = 0; i < 3; ++i)
    if (tt >= i) v += (float)callb[(row - i) * 1536 + i * 512 + o];
  db[id] = (bf)v;
}

// E[b*64+c][p] = YLOC[b][c*16 + (p<512?15:14)][p&511]
__global__ void k_egather(const float* __restrict__ yloc, float* __restrict__ E) {
  long id = (long)blockIdx.x * 256 + threadIdx.x;  // < 262144
  int p = (int)(id & 1023); long r = id >> 10;
  int b = (int)(r >> 6), c = (int)(r & 63);
  int tt = c * 16 + ((p < 512) ? 15 : 14);
  E[id] = yloc[((long)(b << 10) + tt) * 512 + (p & 511)];
}

__global__ void k_shiftb(const float* __restrict__ E, bf* __restrict__ ebs, int sh) {
  long id = (long)blockIdx.x * 256 + threadIdx.x;  // < 262144
  int c = (int)((id >> 10) & 63);
  ebs[id] = (c >= sh) ? (bf)E[id - (long)sh * 1024] : (bf)0.f;
}

__global__ void k_sfinal(const float* __restrict__ E, bf* __restrict__ ssb) {
  long id = (long)blockIdx.x * 256 + threadIdx.x;  // < 262144
  int c = (int)((id >> 10) & 63);
  ssb[id] = (c > 0) ? (bf)E[id - 1024] : (bf)0.f;
}

// y = yloc + CM^{j+1}[o][:]·s ; out = bf16(gelu(y))
__global__ void k_combgelu(const float* __restrict__ yloc, const bf* __restrict__ outh,
                           bf* __restrict__ yg) {
  long id = (long)blockIdx.x * 256 + threadIdx.x;  // < 2097152
  int o = (int)(id & 511); long row = id >> 9;
  int b = (int)(row >> 10), tt = (int)(row & 1023);
  int c = tt >> 4, j = tt & 15;
  long wv = ((long)(j * 512 + o)) * 256 + b * 64 + c;
  float v = yloc[id] + (float)outh[wv];
  yg[id] = (bf)(0.5f * v * (1.f + erff(v * 0.70710678118654752f)));
}

__global__ void k_glures(const bf* __restrict__ g, float* __restrict__ x) {
  long id = (long)blockIdx.x * 256 + threadIdx.x;  // < 2097152
  int o = (int)(id & 511); long row = id >> 9;
  float a = (float)g[row * 1024 + o], bb = (float)g[row * 1024 + 512 + o];
  x[id] = x[id] + a / (1.f + expf(-bb));
}

__global__ void k_cast(const float* __restrict__ in, bf* __restrict__ out, long n4) {
  long id = (long)blockIdx.x * 256 + threadIdx.x;
  if (id >= n4) return;
  float4 v = *(const float4*)(in + id * 4);
  bfv4 o; o[0] = (bf)v.x; o[1] = (bf)v.y; o[2] = (bf)v.z; o[3] = (bf)v.w;
  *(bfv4*)(out + id * 4) = o;
}

__global__ void k_fill(float* p, long n, float v) {
  long id = (long)blockIdx.x * 256 + threadIdx.x;
  if (id < n) p[id] = v;
}

// ---------------- workspace layout ----------------
struct Lay {
  long ZPG, EMBT, PROJT, TOEP, CMPOW, X, MPHITL, MUTL, W1TL, HB, RB, DSLOT, RA, RC, need;
  int nk, fullT;
};
static Lay mkLay(int nk, int fullT) {
  Lay L; long o = 0;
  auto al = [&](long sz) { long r = o; o += (sz + 255) & ~255L; return r; };
  L.nk = nk; L.fullT = fullT;
  L.ZPG   = al(2048);
  L.EMBT  = al(524288);
  L.PROJT = al(524288);
  L.TOEP  = al((fullT ? 24L : (long)nk) * 2097152);
  L.CMPOW = al(17L * 2097152);
  L.X     = al(8388608);
  L.MPHITL= al(12582912);
  L.MUTL  = al(1572864);
  L.W1TL  = al(1048576);
  L.HB    = al(4194304);   // HB | INB | scan W ping-pong (2x 2MB)
  L.RB    = al(4194304);   // HTB | OUTH
  L.DSLOT = al(4194304);   // TT | DELTAB | YGB
  L.RA    = al(8388608);   // DELTA f32
  long rc = (long)nk * 4194304;               // XTC
  if (rc < 12582912) rc = 12582912;           // CALLB
  if (rc < 18874368) rc = 18874368;           // YLOC + E + EBS + SSTB + G
  L.RC    = al(rc);
  L.need  = o;
  return L;
}

extern "C" void kernel_launch(void* const* d_in, const int* in_sizes, int n_in,
                              void* d_out, int out_size, void* d_ws, size_t ws_size,
                              hipStream_t stream) {
  Lay L = mkLay(6, 1);
  if (L.need > (long)ws_size) L = mkLay(3, 1);
  if (L.need > (long)ws_size) L = mkLay(3, 0);
  if (L.need > (long)ws_size) {  // diagnostic: absmax ~= 1e6 + ws_MB
    k_fill<<<8192, 256, 0, stream>>>((float*)d_out, 2097152, 1.0e6f + (float)(ws_size >> 20));
    return;
  }
  const float* inp  = (const float*)d_in[0];
  const float* embw = (const float*)d_in[1];
  const float* embb = (const float*)d_in[2];
  const float* lns  = (const float*)d_in[3];
  const float* lnb  = (const float*)d_in[4];
  const float* m_y  = (const float*)d_in[5];
  const float* m_u  = (const float*)d_in[6];
  const float* mphi = (const float*)d_in[7];
  const float* w1   = (const float*)d_in[8];
  const float* b1   = (const float*)d_in[9];
  const float* pw   = (const float*)d_in[10];
  const float* pb   = (const float*)d_in[11];
  const float* evals = (const float*)d_in[12];
  const float* evecs = (const float*)d_in[13];

  char* w = (char*)d_ws;
  bf*    ZPG   = (bf*)(w + L.ZPG);
  bf*    EMBT  = (bf*)(w + L.EMBT);
  bf*    PROJT = (bf*)(w + L.PROJT);
  bf*    TOEP  = (bf*)(w + L.TOEP);
  bf*    CMPOW = (bf*)(w + L.CMPOW);
  float* X     = (float*)(w + L.X);
  bf*    MPHITL= (bf*)(w + L.MPHITL);
  bf*    MUTL  = (bf*)(w + L.MUTL);
  bf*    W1TL  = (bf*)(w + L.W1TL);
  bf*    HB    = (bf*)(w + L.HB);
  bf*    Wa    = HB;                         // scan ping-pong (HB dead by then)
  bf*    Wb    = HB + 1048576;
  bf*    HTB   = (bf*)(w + L.RB);
  bf*    OUTH  = (bf*)(w + L.RB);
  bf*    TT    = (bf*)(w + L.DSLOT);
  bf*    DELTAB= (bf*)(w + L.DSLOT);
  bf*    YGB   = (bf*)(w + L.DSLOT);
  float* DELTA = (float*)(w + L.RA);
  bf*    XTC   = (bf*)(w + L.RC);
  bf*    CALLB = (bf*)(w + L.RC);
  float* YLOC  = (float*)(w + L.RC);
  float* E     = (float*)(w + L.RC + 8388608);
  bf*    EBS   = (bf*)(w + L.RC + 9437184);
  bf*    SSTB  = (bf*)(w + L.RC + 9961472);
  bf*    G     = (bf*)(w + L.RC + 10485760);
  bf*    INB   = HB;
  hipStream_t st = stream;
  const int nk = L.nk, nchunk = 24 / nk;

  hipMemsetAsync(w + L.ZPG, 0, 2048, st);

  // ---- one-time prep ----
  k_trt<float, bf><<<dim3(8, 8, 1), 256, 0, st>>>(embw, EMBT, 512, 0, 512, 0);
  k_trt<float, bf><<<dim3(8, 8, 1), 256, 0, st>>>(pw, PROJT, 512, 0, 512, 0);
  if (L.fullT)
    k_toep<<<dim3((unsigned)((24L * 1048576) / 256)), 256, 0, st>>>(evecs, evals, TOEP, 0, 24);
  k_cast<<<2048, 256, 0, st>>>(inp, INB, 524288);
  gemm<1,1,0,0,0>(st, 4096, 512, 1, INB, 512, 512, 262144, 0, 0, EMBT, 512, 512, 0, 0x7fffffff,
                  X, 512, 0, nullptr, 0, 0, embb, 512, ZPG);

  for (int l = 0; l < 4; ++l) {
    // --- per-layer prep: CM powers (doubling), weight transposes ---
    k_buildCM<<<8192, 256, 0, st>>>(m_y + (long)l * 524288, CMPOW);
    for (int s = 1; s <= 8; s <<= 1) {
      k_trt<bf, bf><<<dim3(16, 16, 1), 256, 0, st>>>(CMPOW + (long)s * 1048576, TT, 1024, 0, 1024, 0);
      gemm<0,0,1,0,0>(st, 1024, 1024, s, CMPOW + 1048576, 1024, 512, 524288, 1048576, 0,
                      TT, 1024, 512, 0, 0,
                      nullptr, 0, 0, CMPOW + (long)(s + 1) * 1048576, 1024, 1048576, nullptr, 1024, ZPG);
    }
    k_trt<float, bf><<<dim3(192, 8, 1), 256, 0, st>>>(mphi + (long)l * 6291456, MPHITL, 512, 0, 12288, 0);
    k_mut<<<3072, 256, 0, st>>>(m_u + (long)l * 786432, MUTL);
    k_trt<float, bf><<<dim3(8, 16, 1), 256, 0, st>>>(w1 + (long)l * 524288, W1TL, 1024, 0, 512, 0);

    // --- LN -> HB; HTB = per-batch transpose ---
    k_ln<<<4096, 256, 0, st>>>(X, lns + l * 512, lnb + l * 512, HB);
    k_trt<bf, bf><<<dim3(16, 8, 4), 256, 0, st>>>(HB, HTB, 512, 524288, 1024, 524288);

    // --- spectral: Toeplitz conv GEMM -> phi projection (accumulating) ---
    for (int kc = 0; kc < nchunk; ++kc) {
      const bf* tb = TOEP;
      if (L.fullT) tb = TOEP + (long)kc * nk * 1048576;
      else k_toep<<<dim3((unsigned)(((long)nk * 1048576) / 256)), 256, 0, st>>>(evecs, evals, TOEP, kc * nk, nk);
      gemm<0,0,1,0,0>(st, 1024, 512, 4 * nk, tb, 1024, 512, 524288, 1048576, 2,
                      HTB, 1024, 512, 524288, 3,
                      nullptr, 0, 0, XTC, 512, 524288, nullptr, 1024, ZPG);
      if (kc == 0)
        gemm<0,1,0,0,0>(st, 4096, 512, 1, XTC, 512, 2097152, 262144, 0, 0,
                        MPHITL + (long)kc * nk * 512, 12288, 512, 0, 0x7fffffff,
                        DELTA, 512, 0, nullptr, 0, 0, nullptr, nk * 512, ZPG);
      else
        gemm<0,1,0,0,1>(st, 4096, 512, 1, XTC, 512, 2097152, 262144, 0, 0,
                        MPHITL + (long)kc * nk * 512, 12288, 512, 0, 0x7fffffff,
                        DELTA, 512, 0, nullptr, 0, 0, nullptr, nk * 512, ZPG);
    }

    // --- AR terms + deltas ---
    gemm<0,0,1,0,0>(st, 4096, 1536, 1, HB, 512, 512, 262144, 0, 0, MUTL, 512, 512, 0, 0x7fffffff,
                    nullptr, 0, 0, CALLB, 1536, 0, nullptr, 512, ZPG);
    k_deltas3<<<8192, 256, 0, st>>>(DELTA, CALLB, DELTAB);

    // --- local solutions: implicit causal im2col x CM-power blocks ---
    gemm<0,1,0,1,0>(st, 4096, 512, 1, DELTAB, 512, -512, 262144, 0, 0,
                    CMPOW, 1024, 1048576, 0, 0x7fffffff,
                    YLOC, 512, 0, nullptr, 0, 0, nullptr, 8192, ZPG);

    // --- Kogge-Stone chunk-state scan (6 rounds) ---
    k_egather<<<1024, 256, 0, st>>>(YLOC, E);
    const bf* Wc = CMPOW + 16L * 1048576;
    for (int k = 1; k <= 6; ++k) {
      int sh = 1 << (k - 1);
      k_shiftb<<<1024, 256, 0, st>>>(E, EBS, sh);
      gemm<0,1,0,0,1>(st, 256, 1024, 1, EBS, 1024, 512, 524288, 0, 0, Wc, 1024, 512, 0, 0x7fffffff,
                      E, 1024, 0, nullptr, 0, 0, nullptr, 1024, ZPG);
      if (k < 6) {
        k_trt<bf, bf><<<dim3(16, 16, 1), 256, 0, st>>>(Wc, TT, 1024, 0, 1024, 0);
        bf* Wn = (k & 1) ? Wb : Wa;
        gemm<0,0,1,0,0>(st, 1024, 1024, 1, Wc, 1024, 512, 524288, 0, 0, TT, 1024, 512, 0, 0,
                        nullptr, 0, 0, Wn, 1024, 0, nullptr, 1024, ZPG);
        Wc = Wn;
      }
    }
    k_sfinal<<<1024, 256, 0, st>>>(E, SSTB);

    // --- homogeneous completion: one GEMM over full CM^{j+1} rows ---
    gemm<0,0,1,0,0>(st, 8192, 256, 1, CMPOW + 1048576, 1024, 512, 1048576, 0, 0,
                    SSTB, 1024, 512, 0, 0x7fffffff,
                    nullptr, 0, 0, OUTH, 256, 0, nullptr, 1024, ZPG);
    k_combgelu<<<8192, 256, 0, st>>>(YLOC, OUTH, YGB);

    // --- MLP (GLU) + residual ---
    gemm<1,0,1,0,0>(st, 4096, 1024, 1, YGB, 512, 512, 262144, 0, 0, W1TL, 512, 512, 0, 0x7fffffff,
                    nullptr, 0, 0, G, 1024, 0, b1 + (long)l * 1024, 512, ZPG);
    k_glures<<<8192, 256, 0, st>>>(G, X);
  }

  // ---- output projection ----
  k_cast<<<2048, 256, 0, st>>>(X, INB, 524288);
  gemm<1,1,0,0,0>(st, 4096, 512, 1, INB, 512, 512, 262144, 0, 0, PROJT, 512, 512, 0, 0x7fffffff,
                  (float*)d_out, 512, 0, nullptr, 0, 0, pb, 512, ZPG);
}

// Round 4
// 3475.658 us; speedup vs baseline: 3.8522x; 1.4923x over previous
//
#include <hip/hip_runtime.h>
#include <math.h>

typedef __bf16 bf;
typedef __attribute__((ext_vector_type(4))) __bf16 bfv4;
typedef __attribute__((ext_vector_type(8))) __bf16 bfv8;
typedef __attribute__((ext_vector_type(4))) float f32x4;

__device__ __forceinline__ void gload16(const void* g, void* l) {
  __builtin_amdgcn_global_load_lds((const __attribute__((address_space(1))) void*)g,
                                   (__attribute__((address_space(3))) void*)l, 16, 0, 0);
}

// ---------------- generalized GEMM op descriptor ----------------
// C[M,N] = A[M,K] * Bt[N,K]^T, bf16 in, f32 accum, 128x128 tile, BK=32.
// A row addr: (row>>9)*lMa + (row&511)*la ; K addr: blk*lK + (k&511),
// blk = (k>>9) + z*kz (absolute block for split-K). Z: A += (z>>zshA)*sAz,
// B += (z&zmskB)*sBz, C/Cb += z*s{C,Cb}z.
// tMASK=1: causal im2col (valid iff (row&15) >= blk). tMASK=2: scan shift
// (valid iff (row&63) >= maskCmp). Masked lanes load from zero page.
struct GOp {
  const bf* A; long la, lKa, lMa, sAz; int zshA, kzA;
  const bf* B; long lb, lKb, sBz; int zmskB, kzB;
  float* C; long ldc, sCz;
  bf* Cb; long ldcb, sCbz;
  const float* bias; int K, maskCmp, mBlk;
};

template<int tB,int tF32,int tB16,int tMASK,int tACC>
__device__ __forceinline__ void gbody(const GOp g, int z, bf* lsA, bf* lsB, const bf* zpg) {
  const int t = threadIdx.x;
  const long m0 = (long)blockIdx.x * 128, n0 = (long)blockIdx.y * 128;
  const bf* Ap = g.A + (long)(z >> g.zshA) * g.sAz;
  const bf* Bp = g.B + (long)(z & g.zmskB) * g.sBz;
  const int w = t >> 6, l = t & 63;
  const int wm = (w >> 1) * 64, wn = (w & 1) * 64;
  const int lr = l & 15, lk = (l >> 4) * 8;
  const int r0 = t >> 2, ko = (t & 3) * 8;
  const long rowA1 = m0 + r0, rowA2 = rowA1 + 64;
  const long baseA1 = (rowA1 >> 9) * g.lMa + (rowA1 & 511) * g.la;
  const long baseA2 = (rowA2 >> 9) * g.lMa + (rowA2 & 511) * g.la;
  const long baseB1 = (n0 + r0) * g.lb;
  const int zbA = z * g.kzA, zbB = z * g.kzB;
  f32x4 acc[4][4];
  #pragma unroll
  for (int i = 0; i < 4; i++)
    #pragma unroll
    for (int j = 0; j < 4; j++) acc[i][j] = (f32x4){0.f, 0.f, 0.f, 0.f};

  for (int k0 = 0; k0 < g.K; k0 += 32) {
    const int kk = k0 + ko;
    const int bA = (kk >> 9) + zbA, bB = (kk >> 9) + zbB;
    const long ka = (long)bA * g.lKa + (kk & 511);
    const long kb = (long)bB * g.lKb + (kk & 511);
    const bf* ga  = Ap + baseA1 + ka;
    const bf* ga2 = Ap + baseA2 + ka;
    if (tMASK == 1) { if ((int)(rowA1 & 15) < bA) { ga = zpg; ga2 = zpg; } }
    if (tMASK == 2) { if ((int)(rowA1 & 63) < g.maskCmp) { ga = zpg; ga2 = zpg; } }
    const bf* gb = Bp + baseB1 + kb;
    gload16(ga,            &lsA[t * 8]);
    gload16(ga2,           &lsA[2048 + t * 8]);
    gload16(gb,            &lsB[t * 8]);
    gload16(gb + 64 * g.lb, &lsB[2048 + t * 8]);
    __syncthreads();
    bfv8 av[4], bv[4];
    #pragma unroll
    for (int i = 0; i < 4; i++) av[i] = *(const bfv8*)&lsA[(wm + i * 16 + lr) * 32 + lk];
    #pragma unroll
    for (int i = 0; i < 4; i++) bv[i] = *(const bfv8*)&lsB[(wn + i * 16 + lr) * 32 + lk];
    #pragma unroll
    for (int i = 0; i < 4; i++)
      #pragma unroll
      for (int j = 0; j < 4; j++)
        acc[i][j] = __builtin_amdgcn_mfma_f32_16x16x32_bf16(av[i], bv[j], acc[i][j], 0, 0, 0);
    __syncthreads();
  }
  const int orow = (l >> 4) * 4, ocol = lr;
  #pragma unroll
  for (int i = 0; i < 4; i++)
    #pragma unroll
    for (int j = 0; j < 4; j++) {
      long col = n0 + wn + j * 16 + ocol;
      float bb = tB ? g.bias[col] : 0.f;
      #pragma unroll
      for (int r = 0; r < 4; r++) {
        long row = m0 + wm + i * 16 + orow + r;
        float v = acc[i][j][r] + bb;
        if (tF32) {
          long idx = (long)z * g.sCz + row * g.ldc + col;
          if (tACC) v += g.C[idx];
          g.C[idx] = v;
        }
        if (tB16) g.Cb[(long)z * g.sCbz + row * g.ldcb + col] = (bf)v;
      }
    }
}

// merged kernel: z < gridDim.z-1 (or tSPEC=0): main op; last z: special op.
template<int tB,int tF32,int tB16,int tMASK,int tACC,int tSPEC,
         int sB,int sF32,int sB16,int sMASK,int sACC>
__global__ __launch_bounds__(256) void gemm_k(GOp g, GOp gx, const bf* __restrict__ zpg) {
  __shared__ bf lsA[4096], lsB[4096];
  int z = blockIdx.z;
  if (tSPEC && z == (int)gridDim.z - 1) {
    if ((int)blockIdx.x >= gx.mBlk) return;
    gbody<sB,sF32,sB16,sMASK,sACC>(gx, 0, lsA, lsB, zpg);
  } else {
    gbody<tB,tF32,tB16,tMASK,tACC>(g, z, lsA, lsB, zpg);
  }
}

static inline GOp mkop(const void* A, long la, long lKa, long lMa, long sAz, int zshA, int kzA,
                       const void* B, long lb, long lKb, long sBz, int zmskB, int kzB,
                       void* C, long ldc, long sCz, void* Cb, long ldcb, long sCbz,
                       const void* bias, int K, int maskCmp, int mBlk) {
  GOp g;
  g.A = (const bf*)A; g.la = la; g.lKa = lKa; g.lMa = lMa; g.sAz = sAz; g.zshA = zshA; g.kzA = kzA;
  g.B = (const bf*)B; g.lb = lb; g.lKb = lKb; g.sBz = sBz; g.zmskB = zmskB; g.kzB = kzB;
  g.C = (float*)C; g.ldc = ldc; g.sCz = sCz;
  g.Cb = (bf*)Cb; g.ldcb = ldcb; g.sCbz = sCbz;
  g.bias = (const float*)bias; g.K = K; g.maskCmp = maskCmp; g.mBlk = mBlk;
  return g;
}

template<int tB,int tF32,int tB16,int tMASK,int tACC,int tSPEC=0,
         int sB=0,int sF32=0,int sB16=0,int sMASK=0,int sACC=0>
static inline void LG(hipStream_t st, int gx, int gy, int gz, const GOp& g, const GOp& gs, const bf* zpg) {
  gemm_k<tB,tF32,tB16,tMASK,tACC,tSPEC,sB,sF32,sB16,sMASK,sACC>
      <<<dim3(gx, gy, gz), 256, 0, st>>>(g, gs, zpg);
}

// ---------------- small kernels ----------------

template<typename TI, typename TO>
__global__ __launch_bounds__(256) void k_trt(const TI* __restrict__ in, TO* __restrict__ out,
                                             long ldin, long inz, long ldout, long outz) {
  __shared__ float tile[64][65];
  int z = blockIdx.z;
  int c0 = blockIdx.x * 64, r0 = blockIdx.y * 64;
  int tx = threadIdx.x & 63, ty = threadIdx.x >> 6;
  #pragma unroll
  for (int i = ty; i < 64; i += 4) tile[i][tx] = (float)in[(long)z * inz + (long)(c0 + i) * ldin + r0 + tx];
  __syncthreads();
  #pragma unroll
  for (int i = ty; i < 64; i += 4) out[(long)z * outz + (long)(r0 + i) * ldout + c0 + tx] = (TO)tile[tx][i];
}

__global__ void k_mut(const float* __restrict__ mul_, bf* __restrict__ out) {
  long id = (long)blockIdx.x * 256 + threadIdx.x;  // < 786432
  long r = id >> 9; int d = (int)(id & 511);
  int i = (int)(r >> 9), o = (int)(r & 511);
  out[id] = (bf)mul_[(long)o * 1536 + d * 3 + i];
}

// CMPOW[0] = I(1024), CMPOW[1] = [[A,B],[I,0]]
__global__ void k_buildCM(const float* __restrict__ myl, bf* __restrict__ cmpow) {
  long id = (long)blockIdx.x * 256 + threadIdx.x;  // < 2097152
  int half = (int)(id >> 20);
  int r = (int)(id & 1048575);
  int p = r >> 10, q = r & 1023;
  float v;
  if (half == 0) v = (p == q) ? 1.f : 0.f;
  else if (p < 512) v = myl[(long)p * 1024 + q];
  else v = (q == p - 512) ? 1.f : 0.f;
  cmpow[id] = (bf)v;
}

// Toeplitz filter tables: out[kl][t][s] = (t>=s)? evec[t-s][k0+kl]*evals[k0+kl]^0.25 : 0
__global__ void k_toep(const float* __restrict__ evecs, const float* __restrict__ evals,
                       bf* __restrict__ out, int k0, int nkk) {
  long id = (long)blockIdx.x * 256 + threadIdx.x;
  if (id >= (long)nkk * 1048576) return;
  int kl = (int)(id >> 20);
  int r = (int)(id & 1048575);
  int tt = r >> 10, s = r & 1023;
  int k = k0 + kl;
  float v = 0.f;
  if (tt >= s) v = evecs[(long)(tt - s) * 24 + k] * powf(evals[k], 0.25f);
  out[id] = (bf)v;
}

__global__ __launch_bounds__(256) void k_ln(const float* __restrict__ x, const float* __restrict__ sc,
                                            const float* __restrict__ bi, bf* __restrict__ hb) {
  __shared__ float red[8];
  long row = blockIdx.x;
  const float* xr = x + row * 512;
  int t = threadIdx.x;
  float a = xr[t], b2 = xr[t + 256];
  float s = a + b2;
  #pragma unroll
  for (int o = 32; o; o >>= 1) s += __shfl_down(s, o, 64);
  if ((t & 63) == 0) red[t >> 6] = s;
  __syncthreads();
  float mu = (red[0] + red[1] + red[2] + red[3]) * (1.f / 512.f);
  __syncthreads();
  float c1 = a - mu, c2 = b2 - mu;
  float qq = c1 * c1 + c2 * c2;
  #pragma unroll
  for (int o = 32; o; o >>= 1) qq += __shfl_down(qq, o, 64);
  if ((t & 63) == 0) red[t >> 6] = qq;
  __syncthreads();
  float var = (red[0] + red[1] + red[2] + red[3]) * (1.f / 512.f);
  float rs = rsqrtf(var + 1e-5f);
  hb[row * 512 + t]       = (bf)(c1 * rs * sc[t] + bi[t]);
  hb[row * 512 + t + 256] = (bf)(c2 * rs * sc[t + 256] + bi[t + 256]);
}

// DELTAB = bf16(sum_z DP[z] + shifted AR terms)
__global__ void k_deltasS(const float* __restrict__ dp, long stride, int S,
                          const bf* __restrict__ callb, bf* __restrict__ db) {
  long id = (long)blockIdx.x * 256 + threadIdx.x;  // < 2097152
  int o = (int)(id & 511); long row = id >> 9; int tt = (int)(row & 1023);
  float v = 0.f;
  for (int zz = 0; zz < S; ++zz) v += dp[(long)zz * stride + id];
  for (int i = 0; i < 3; ++i)
    if (tt >= i) v += (float)callb[(row - i) * 1536 + i * 512 + o];
  db[id] = (bf)v;
}

// E[b*64+c][p] = sum_z YLOCp[z][b][c*16 + (p<512?15:14)][p&511] ; dual f32+bf16 out
__global__ void k_egather(const float* __restrict__ dp, long stride, int S,
                          float* __restrict__ E, bf* __restrict__ eb0) {
  long id = (long)blockIdx.x * 256 + threadIdx.x;  // < 262144
  int p = (int)(id & 1023); long r = id >> 10;
  int b = (int)(r >> 6), c = (int)(r & 63);
  int tq = c * 16 + ((p < 512) ? 15 : 14);
  long idx = ((long)(b << 10) + tq) * 512 + (p & 511);
  float v = 0.f;
  for (int zz = 0; zz < S; ++zz) v += dp[(long)zz * stride + idx];
  E[id] = v; eb0[id] = (bf)v;
}

__global__ void k_sfinal(const float* __restrict__ E, bf* __restrict__ ssb) {
  long id = (long)blockIdx.x * 256 + threadIdx.x;  // < 262144
  int c = (int)((id >> 10) & 63);
  ssb[id] = (c > 0) ? (bf)E[id - 1024] : (bf)0.f;
}

// y = sum_z YLOCp[z] + CM^{j+1}-row dot s ; out = bf16(gelu(y))
__global__ void k_combgelu(const float* __restrict__ dp, long stride, int S,
                           const bf* __restrict__ outh, bf* __restrict__ yg) {
  long id = (long)blockIdx.x * 256 + threadIdx.x;  // < 2097152
  int o = (int)(id & 511); long row = id >> 9;
  int b = (int)(row >> 10), tt = (int)(row & 1023);
  int c = tt >> 4, j = tt & 15;
  long wv = ((long)(j * 512 + o)) * 256 + b * 64 + c;
  float v = (float)outh[wv];
  for (int zz = 0; zz < S; ++zz) v += dp[(long)zz * stride + id];
  yg[id] = (bf)(0.5f * v * (1.f + erff(v * 0.70710678118654752f)));
}

__global__ void k_glures(const bf* __restrict__ g, float* __restrict__ x) {
  long id = (long)blockIdx.x * 256 + threadIdx.x;  // < 2097152
  int o = (int)(id & 511); long row = id >> 9;
  float a = (float)g[row * 1024 + o], bb = (float)g[row * 1024 + 512 + o];
  x[id] = x[id] + a / (1.f + expf(-bb));
}

__global__ void k_cast(const float* __restrict__ in, bf* __restrict__ out, long n4) {
  long id = (long)blockIdx.x * 256 + threadIdx.x;
  if (id >= n4) return;
  float4 v = *(const float4*)(in + id * 4);
  bfv4 o; o[0] = (bf)v.x; o[1] = (bf)v.y; o[2] = (bf)v.z; o[3] = (bf)v.w;
  *(bfv4*)(out + id * 4) = o;
}

__global__ void k_fill(float* p, long n, float v) {
  long id = (long)blockIdx.x * 256 + threadIdx.x;
  if (id < n) p[id] = v;
}

// ---------------- workspace layout (byte offsets) ----------------
struct Lay {
  long ZPG, EMBT, PROJT, TOEP, CMPOW, CMT2, WU, X, MPHITL, MUTL, W1TL,
       HB, HTB, DSLOT, DP, RC, E, EB0, EB1, SSTB, need;
  int nk, S, fullT;
};
static Lay mkLay(int nk, int S, int fullT) {
  Lay L; long o = 0;
  auto al = [&](long sz) { long r = o; o += (sz + 255) & ~255L; return r; };
  L.nk = nk; L.S = S; L.fullT = fullT;
  L.ZPG   = al(4096);
  L.EMBT  = al(524288);
  L.PROJT = al(524288);
  L.TOEP  = al((long)(fullT ? 24 : nk) * 2097152);
  L.CMPOW = al(17L * 2097152);
  L.CMT2  = al(5L * 2097152);
  L.WU    = al(8388608);
  L.X     = al(8388608);
  L.MPHITL= al(12582912);
  L.MUTL  = al(1572864);
  L.W1TL  = al(1048576);
  L.HB    = al(4194304);
  L.HTB   = al(4194304);
  L.DSLOT = al(4194304);                 // DELTAB | YGB
  L.DP    = al((long)S * 8388608);       // f32 partials (phi, then yloc)
  long rc = (long)nk * 4194304;          // XTC
  if (rc < 16777216) rc = 16777216;      // CALLB(12.58M)+OUTH(4.19M); G(8.39M)
  L.RC    = al(rc);
  L.E     = al(1048576);
  L.EB0   = al(524288);
  L.EB1   = al(524288);
  L.SSTB  = al(524288);
  L.need  = o;
  return L;
}

extern "C" void kernel_launch(void* const* d_in, const int* in_sizes, int n_in,
                              void* d_out, int out_size, void* d_ws, size_t ws_size,
                              hipStream_t stream) {
  Lay L = mkLay(8, 4, 1);                         // ~212 MB
  if (L.need > (long)ws_size) L = mkLay(8, 4, 0); // ~178 MB
  if (L.need > (long)ws_size) L = mkLay(4, 2, 0); // ~136 MB
  if (L.need > (long)ws_size) L = mkLay(4, 1, 0); // ~128 MB
  if (L.need > (long)ws_size) {                   // diagnostic: absmax ~= 1e6 + ws_MB
    k_fill<<<8192, 256, 0, stream>>>((float*)d_out, 2097152, 1.0e6f + (float)(ws_size >> 20));
    return;
  }
  const float* inp  = (const float*)d_in[0];
  const float* embw = (const float*)d_in[1];
  const float* embb = (const float*)d_in[2];
  const float* lns  = (const float*)d_in[3];
  const float* lnb  = (const float*)d_in[4];
  const float* m_y  = (const float*)d_in[5];
  const float* m_u  = (const float*)d_in[6];
  const float* mphi = (const float*)d_in[7];
  const float* w1   = (const float*)d_in[8];
  const float* b1   = (const float*)d_in[9];
  const float* pw   = (const float*)d_in[10];
  const float* pb   = (const float*)d_in[11];
  const float* evals = (const float*)d_in[12];
  const float* evecs = (const float*)d_in[13];

  char* w = (char*)d_ws;
  bf*    ZPG   = (bf*)(w + L.ZPG);
  bf*    EMBT  = (bf*)(w + L.EMBT);
  bf*    PROJT = (bf*)(w + L.PROJT);
  bf*    TOEP  = (bf*)(w + L.TOEP);
  bf*    CMPOW = (bf*)(w + L.CMPOW);
  bf*    CMT2  = (bf*)(w + L.CMT2);
  bf*    WUa   = (bf*)(w + L.WU);                 // W | U pair (1M elems each)
  bf*    WUb   = (bf*)(w + L.WU + 4194304);
  float* X     = (float*)(w + L.X);
  bf*    MPHITL= (bf*)(w + L.MPHITL);
  bf*    MUTL  = (bf*)(w + L.MUTL);
  bf*    W1TL  = (bf*)(w + L.W1TL);
  bf*    HB    = (bf*)(w + L.HB);
  bf*    HTB   = (bf*)(w + L.HTB);
  bf*    DELTAB= (bf*)(w + L.DSLOT);
  bf*    YGB   = (bf*)(w + L.DSLOT);
  float* DP    = (float*)(w + L.DP);
  bf*    XTC   = (bf*)(w + L.RC);
  bf*    CALLB = (bf*)(w + L.RC);
  bf*    OUTH  = (bf*)(w + L.RC + 12582912);
  bf*    G     = (bf*)(w + L.RC);
  float* E     = (float*)(w + L.E);
  bf*    EB0   = (bf*)(w + L.EB0);
  bf*    EB1   = (bf*)(w + L.EB1);
  bf*    SSTB  = (bf*)(w + L.SSTB);
  bf*    INB   = HB;
  hipStream_t st = stream;
  const int nk = L.nk, S = L.S, nchunk = 24 / nk;
  const long DPS = 2097152;                       // DP z-stride in f32 elems
  const int Kcphi = nk * 512 / S, kzphi = Kcphi >> 9;
  const int Kcy = 8192 / S, kzy = Kcy >> 9;
  GOp gnull = {};

  hipMemsetAsync(w + L.ZPG, 0, 4096, st);

  // ---- one-time prep ----
  k_trt<float, bf><<<dim3(8, 8, 1), 256, 0, st>>>(embw, EMBT, 512, 0, 512, 0);
  k_trt<float, bf><<<dim3(8, 8, 1), 256, 0, st>>>(pw, PROJT, 512, 0, 512, 0);
  if (L.fullT)
    k_toep<<<dim3((unsigned)((24L * 1048576) / 256)), 256, 0, st>>>(evecs, evals, TOEP, 0, 24);
  k_cast<<<2048, 256, 0, st>>>(inp, INB, 524288);
  LG<1,1,0,0,0>(st, 32, 4, 1,
      mkop(INB, 512, 512, 262144, 0, 30, 0, EMBT, 512, 512, 0, 0, 0,
           X, 512, 0, nullptr, 0, 0, embb, 512, 0, 0), gnull, ZPG);

  for (int l = 0; l < 4; ++l) {
    // --- CM powers via merged dual-chain doubling (no transposes) ---
    k_buildCM<<<8192, 256, 0, st>>>(m_y + (long)l * 524288, CMPOW);
    k_trt<bf, bf><<<dim3(16, 16, 1), 256, 0, st>>>(CMPOW + 1048576, CMT2, 1024, 0, 1024, 0);
    for (int r = 0; r < 4; ++r) {
      int s = 1 << r;
      GOp mn = mkop(CMPOW + 1048576, 1024, 512, 524288, 1048576, 0, 0,
                    CMT2 + (long)r * 1048576, 1024, 512, 0, 0, 0,
                    nullptr, 0, 0, CMPOW + (long)(s + 1) * 1048576, 1024, 1048576,
                    nullptr, 1024, 0, 0);
      GOp sp = mkop(CMT2 + (long)r * 1048576, 1024, 512, 524288, 0, 30, 0,
                    CMPOW + (long)s * 1048576, 1024, 512, 0, 0, 0,
                    nullptr, 0, 0, CMT2 + (long)(r + 1) * 1048576, 1024, 0,
                    nullptr, 1024, 0, 8);
      LG<0,0,1,0,0, 1, 0,0,1,0,0>(st, 8, 8, s + 1, mn, sp, ZPG);
    }
    // --- per-layer weight prep ---
    k_trt<float, bf><<<dim3(192, 8, 1), 256, 0, st>>>(mphi + (long)l * 6291456, MPHITL, 512, 0, 12288, 0);
    k_mut<<<3072, 256, 0, st>>>(m_u + (long)l * 786432, MUTL);
    k_trt<float, bf><<<dim3(8, 16, 1), 256, 0, st>>>(w1 + (long)l * 524288, W1TL, 1024, 0, 512, 0);

    // --- LN -> HB ; HTB per-batch transpose ---
    k_ln<<<4096, 256, 0, st>>>(X, lns + l * 512, lnb + l * 512, HB);
    k_trt<bf, bf><<<dim3(16, 8, 4), 256, 0, st>>>(HB, HTB, 512, 524288, 1024, 524288);

    // --- spectral: Toeplitz conv -> split-K phi projection into DP partials ---
    for (int kc = 0; kc < nchunk; ++kc) {
      const bf* tb = TOEP;
      if (L.fullT) tb = TOEP + (long)kc * nk * 1048576;
      else k_toep<<<dim3((unsigned)(((long)nk * 1048576) / 256)), 256, 0, st>>>(evecs, evals, TOEP, kc * nk, nk);
      LG<0,0,1,0,0>(st, 8, 4, 4 * nk,
          mkop(tb, 1024, 512, 524288, 1048576, 2, 0,
               HTB, 1024, 512, 524288, 3, 0,
               nullptr, 0, 0, XTC, 512, 524288, nullptr, 1024, 0, 0), gnull, ZPG);
      GOp pg = mkop(XTC, 512, 2097152, 262144, 0, 30, kzphi,
                    MPHITL + (long)kc * nk * 512, 12288, 512, 0, 0, kzphi,
                    DP, 512, DPS, nullptr, 0, 0, nullptr, Kcphi, 0, 0);
      if (kc == 0) LG<0,1,0,0,0>(st, 32, 4, S, pg, gnull, ZPG);
      else         LG<0,1,0,0,1>(st, 32, 4, S, pg, gnull, ZPG);
    }

    // --- AR terms + deltas (sums DP partials) ---
    LG<0,0,1,0,0>(st, 32, 12, 1,
        mkop(HB, 512, 512, 262144, 0, 30, 0, MUTL, 512, 512, 0, 0, 0,
             nullptr, 0, 0, CALLB, 1536, 0, nullptr, 512, 0, 0), gnull, ZPG);
    k_deltasS<<<8192, 256, 0, st>>>(DP, DPS, S, CALLB, DELTAB);

    // --- local solutions: causal im2col x CM-power blocks, split-K into DP ---
    LG<0,1,0,1,0>(st, 32, 4, S,
        mkop(DELTAB, 512, -512, 262144, 0, 30, kzy,
             CMPOW, 1024, 1048576, 0, 0, kzy,
             DP, 512, DPS, nullptr, 0, 0, nullptr, Kcy, 0, 0), gnull, ZPG);

    // --- Kogge-Stone chunk-state scan: merged {W/U squaring | E-update} ---
    k_egather<<<1024, 256, 0, st>>>(DP, DPS, S, E, EB0);
    const bf* Wc = CMPOW + 16L * 1048576;         // W^1 = T = CM^16
    const bf* Uc = CMT2 + 4L * 1048576;           // U^1 = (CM^16)^T
    bf* EBc = EB0; bf* EBn = EB1;
    bf* WUn = WUa;
    for (int k = 1; k <= 5; ++k) {
      int sh = 1 << (k - 1);
      GOp mn = mkop(Wc, 1024, 512, 524288, (long)(Uc - Wc), 0, 0,
                    Uc, 1024, 512, (long)(Wc - Uc), 1, 0,
                    nullptr, 0, 0, WUn, 1024, 1048576, nullptr, 1024, 0, 0);
      GOp sp = mkop(EBc - (long)sh * 1024, 1024, 512, 524288, 0, 30, 0,
                    Wc, 1024, 512, 0, 0, 0,
                    E, 1024, 0, EBn, 1024, 0, nullptr, 1024, sh, 2);
      LG<0,0,1,0,0, 1, 0,1,1,2,1>(st, 8, 8, 3, mn, sp, ZPG);
      Wc = WUn; Uc = WUn + 1048576;
      WUn = (k & 1) ? WUb : WUa;
      bf* tmp = EBc; EBc = EBn; EBn = tmp;
    }
    LG<0,1,0,2,1>(st, 2, 8, 1,
        mkop(EBc - 32L * 1024, 1024, 512, 524288, 0, 30, 0,
             Wc, 1024, 512, 0, 0, 0,
             E, 1024, 0, nullptr, 0, 0, nullptr, 1024, 32, 0), gnull, ZPG);
    k_sfinal<<<1024, 256, 0, st>>>(E, SSTB);

    // --- homogeneous completion + gelu + MLP(GLU) + residual ---
    LG<0,0,1,0,0>(st, 64, 2, 1,
        mkop(CMPOW + 1048576, 1024, 512, 1048576, 0, 30, 0,
             SSTB, 1024, 512, 0, 0, 0,
             nullptr, 0, 0, OUTH, 256, 0, nullptr, 1024, 0, 0), gnull, ZPG);
    k_combgelu<<<8192, 256, 0, st>>>(DP, DPS, S, OUTH, YGB);
    LG<1,0,1,0,0>(st, 32, 8, 1,
        mkop(YGB, 512, 512, 262144, 0, 30, 0, W1TL, 512, 512, 0, 0, 0,
             nullptr, 0, 0, G, 1024, 0, b1 + (long)l * 1024, 512, 0, 0), gnull, ZPG);
    k_glures<<<8192, 256, 0, st>>>(G, X);
  }

  // ---- output projection ----
  k_cast<<<2048, 256, 0, st>>>(X, INB, 524288);
  LG<1,1,0,0,0>(st, 32, 4, 1,
      mkop(INB, 512, 512, 262144, 0, 30, 0, PROJT, 512, 512, 0, 0, 0,
           (float*)d_out, 512, 0, nullptr, 0, 0, pb, 512, 0, 0), gnull, ZPG);
}

// Round 5
// 3448.801 us; speedup vs baseline: 3.8822x; 1.0078x over previous
//
#include <hip/hip_runtime.h>
#include <math.h>

typedef __bf16 bf;
typedef __attribute__((ext_vector_type(4))) __bf16 bfv4;
typedef __attribute__((ext_vector_type(8))) __bf16 bfv8;
typedef __attribute__((ext_vector_type(4))) float f32x4;

__device__ __forceinline__ void gload16(const void* g, void* l) {
  __builtin_amdgcn_global_load_lds((const __attribute__((address_space(1))) void*)g,
                                   (__attribute__((address_space(3))) void*)l, 16, 0, 0);
}

// ---------------- generalized GEMM op descriptor ----------------
// C[M,N] = A[M,K] * Bt[N,K]^T, bf16 in, f32 accum, 128x128 tile, BK=32.
// A row addr: (row>>9)*lMa + (row&511)*la ; K addr: blk*lK + (k&511),
// blk = (k>>9) + z*kz (absolute block for split-K). Z: A += (z>>zshA)*sAz,
// B += (z&zmskB)*sBz, C/Cb += z*s{C,Cb}z.
// tMASK=1: causal im2col (valid iff (row&15) >= blk). tMASK=2: scan shift
// (valid iff (row&63) >= maskCmp). Masked lanes load from zero page.
struct GOp {
  const bf* A; long la, lKa, lMa, sAz; int zshA, kzA;
  const bf* B; long lb, lKb, sBz; int zmskB, kzB;
  float* C; long ldc, sCz;
  bf* Cb; long ldcb, sCbz;
  const float* bias; int K, maskCmp, mBlk;
};

template<int tB,int tF32,int tB16,int tMASK,int tACC>
__device__ __forceinline__ void gbody(const GOp g, int z, bf* lsA, bf* lsB, const bf* zpg) {
  const int t = threadIdx.x;
  const long m0 = (long)blockIdx.x * 128, n0 = (long)blockIdx.y * 128;
  const bf* Ap = g.A + (long)(z >> g.zshA) * g.sAz;
  const bf* Bp = g.B + (long)(z & g.zmskB) * g.sBz;
  const int w = t >> 6, l = t & 63;
  const int wm = (w >> 1) * 64, wn = (w & 1) * 64;
  const int lr = l & 15, lk = (l >> 4) * 8;
  const int r0 = t >> 2, ko = (t & 3) * 8;
  const long rowA1 = m0 + r0, rowA2 = rowA1 + 64;
  const long baseA1 = (rowA1 >> 9) * g.lMa + (rowA1 & 511) * g.la;
  const long baseA2 = (rowA2 >> 9) * g.lMa + (rowA2 & 511) * g.la;
  const long baseB1 = (n0 + r0) * g.lb;
  const int zbA = z * g.kzA, zbB = z * g.kzB;
  f32x4 acc[4][4];
  #pragma unroll
  for (int i = 0; i < 4; i++)
    #pragma unroll
    for (int j = 0; j < 4; j++) acc[i][j] = (f32x4){0.f, 0.f, 0.f, 0.f};

  for (int k0 = 0; k0 < g.K; k0 += 32) {
    const int kk = k0 + ko;
    const int bA = (kk >> 9) + zbA, bB = (kk >> 9) + zbB;
    const long ka = (long)bA * g.lKa + (kk & 511);
    const long kb = (long)bB * g.lKb + (kk & 511);
    const bf* ga  = Ap + baseA1 + ka;
    const bf* ga2 = Ap + baseA2 + ka;
    if (tMASK == 1) { if ((int)(rowA1 & 15) < bA) { ga = zpg; ga2 = zpg; } }
    if (tMASK == 2) { if ((int)(rowA1 & 63) < g.maskCmp) { ga = zpg; ga2 = zpg; } }
    const bf* gb = Bp + baseB1 + kb;
    gload16(ga,            &lsA[t * 8]);
    gload16(ga2,           &lsA[2048 + t * 8]);
    gload16(gb,            &lsB[t * 8]);
    gload16(gb + 64 * g.lb, &lsB[2048 + t * 8]);
    __syncthreads();
    bfv8 av[4], bv[4];
    #pragma unroll
    for (int i = 0; i < 4; i++) av[i] = *(const bfv8*)&lsA[(wm + i * 16 + lr) * 32 + lk];
    #pragma unroll
    for (int i = 0; i < 4; i++) bv[i] = *(const bfv8*)&lsB[(wn + i * 16 + lr) * 32 + lk];
    #pragma unroll
    for (int i = 0; i < 4; i++)
      #pragma unroll
      for (int j = 0; j < 4; j++)
        acc[i][j] = __builtin_amdgcn_mfma_f32_16x16x32_bf16(av[i], bv[j], acc[i][j], 0, 0, 0);
    __syncthreads();
  }
  const int orow = (l >> 4) * 4, ocol = lr;
  #pragma unroll
  for (int i = 0; i < 4; i++)
    #pragma unroll
    for (int j = 0; j < 4; j++) {
      long col = n0 + wn + j * 16 + ocol;
      float bb = tB ? g.bias[col] : 0.f;
      #pragma unroll
      for (int r = 0; r < 4; r++) {
        long row = m0 + wm + i * 16 + orow + r;
        float v = acc[i][j][r] + bb;
        if (tF32) {
          long idx = (long)z * g.sCz + row * g.ldc + col;
          if (tACC) v += g.C[idx];
          g.C[idx] = v;
        }
        if (tB16) g.Cb[(long)z * g.sCbz + row * g.ldcb + col] = (bf)v;
      }
    }
}

// merged kernel: z < gridDim.z-1 (or tSPEC=0): main op; last z: special op.
template<int tB,int tF32,int tB16,int tMASK,int tACC,int tSPEC,
         int sB,int sF32,int sB16,int sMASK,int sACC>
__global__ __launch_bounds__(256) void gemm_k(GOp g, GOp gx, const bf* __restrict__ zpg) {
  __shared__ bf lsA[4096], lsB[4096];
  int z = blockIdx.z;
  if (tSPEC && z == (int)gridDim.z - 1) {
    if ((int)blockIdx.x >= gx.mBlk) return;
    gbody<sB,sF32,sB16,sMASK,sACC>(gx, 0, lsA, lsB, zpg);
  } else {
    gbody<tB,tF32,tB16,tMASK,tACC>(g, z, lsA, lsB, zpg);
  }
}

static inline GOp mkop(const void* A, long la, long lKa, long lMa, long sAz, int zshA, int kzA,
                       const void* B, long lb, long lKb, long sBz, int zmskB, int kzB,
                       void* C, long ldc, long sCz, void* Cb, long ldcb, long sCbz,
                       const void* bias, int K, int maskCmp, int mBlk) {
  GOp g;
  g.A = (const bf*)A; g.la = la; g.lKa = lKa; g.lMa = lMa; g.sAz = sAz; g.zshA = zshA; g.kzA = kzA;
  g.B = (const bf*)B; g.lb = lb; g.lKb = lKb; g.sBz = sBz; g.zmskB = zmskB; g.kzB = kzB;
  g.C = (float*)C; g.ldc = ldc; g.sCz = sCz;
  g.Cb = (bf*)Cb; g.ldcb = ldcb; g.sCbz = sCbz;
  g.bias = (const float*)bias; g.K = K; g.maskCmp = maskCmp; g.mBlk = mBlk;
  return g;
}

template<int tB,int tF32,int tB16,int tMASK,int tACC,int tSPEC=0,
         int sB=0,int sF32=0,int sB16=0,int sMASK=0,int sACC=0>
static inline void LG(hipStream_t st, int gx, int gy, int gz, const GOp& g, const GOp& gs, const bf* zpg) {
  gemm_k<tB,tF32,tB16,tMASK,tACC,tSPEC,sB,sF32,sB16,sMASK,sACC>
      <<<dim3(gx, gy, gz), 256, 0, st>>>(g, gs, zpg);
}

// ---------------- small kernels ----------------

template<typename TI, typename TO>
__global__ __launch_bounds__(256) void k_trt(const TI* __restrict__ in, TO* __restrict__ out,
                                             long ldin, long inz, long ldout, long outz) {
  __shared__ float tile[64][65];
  int z = blockIdx.z;
  int c0 = blockIdx.x * 64, r0 = blockIdx.y * 64;
  int tx = threadIdx.x & 63, ty = threadIdx.x >> 6;
  #pragma unroll
  for (int i = ty; i < 64; i += 4) tile[i][tx] = (float)in[(long)z * inz + (long)(c0 + i) * ldin + r0 + tx];
  __syncthreads();
  #pragma unroll
  for (int i = ty; i < 64; i += 4) out[(long)z * outz + (long)(r0 + i) * ldout + c0 + tx] = (TO)tile[tx][i];
}

// scaled transpose-cast (for m_phi^T): out[r][c] = bf16(in[c][r] * scl[c>>9])
__global__ __launch_bounds__(256) void k_trtS(const float* __restrict__ in, bf* __restrict__ out,
                                              long ldin, long ldout, const float* __restrict__ scl) {
  __shared__ float tile[64][65];
  int c0 = blockIdx.x * 64, r0 = blockIdx.y * 64;
  int tx = threadIdx.x & 63, ty = threadIdx.x >> 6;
  #pragma unroll
  for (int i = ty; i < 64; i += 4) tile[i][tx] = in[(long)(c0 + i) * ldin + r0 + tx];
  __syncthreads();
  float sc = scl[(c0 + tx) >> 9];
  #pragma unroll
  for (int i = ty; i < 64; i += 4) out[(long)(r0 + i) * ldout + c0 + tx] = (bf)(tile[tx][i] * sc);
}

__global__ void k_scl(const float* __restrict__ evals, float* __restrict__ scl) {
  int k = threadIdx.x;
  if (k < 24) scl[k] = powf(evals[k], 0.25f);
}

__global__ void k_mut(const float* __restrict__ mul_, bf* __restrict__ out) {
  long id = (long)blockIdx.x * 256 + threadIdx.x;  // < 786432
  long r = id >> 9; int d = (int)(id & 511);
  int i = (int)(r >> 9), o = (int)(r & 511);
  out[id] = (bf)mul_[(long)o * 1536 + d * 3 + i];
}

// CMPOW[0] = I(1024), CMPOW[1] = [[A,B],[I,0]]
__global__ void k_buildCM(const float* __restrict__ myl, bf* __restrict__ cmpow) {
  long id = (long)blockIdx.x * 256 + threadIdx.x;  // < 2097152
  int half = (int)(id >> 20);
  int r = (int)(id & 1048575);
  int p = r >> 10, q = r & 1023;
  float v;
  if (half == 0) v = (p == q) ? 1.f : 0.f;
  else if (p < 512) v = myl[(long)p * 1024 + q];
  else v = (q == p - 512) ? 1.f : 0.f;
  cmpow[id] = (bf)v;
}

// Toeplitz filter tables (scale folded into m_phi^T): out[kl][t][s] = (t>=s)? evec[t-s][k0+kl] : 0
__global__ void k_toep(const float* __restrict__ evecs, bf* __restrict__ out, int k0, int nkk) {
  long id = (long)blockIdx.x * 256 + threadIdx.x;
  if (id >= (long)nkk * 1048576) return;
  int kl = (int)(id >> 20);
  int r = (int)(id & 1048575);
  int tt = r >> 10, s = r & 1023;
  float v = 0.f;
  if (tt >= s) v = evecs[(long)(tt - s) * 24 + k0 + kl];
  out[id] = (bf)v;
}

__global__ __launch_bounds__(256) void k_ln(const float* __restrict__ x, const float* __restrict__ sc,
                                            const float* __restrict__ bi, bf* __restrict__ hb) {
  __shared__ float red[8];
  long row = blockIdx.x;
  const float* xr = x + row * 512;
  int t = threadIdx.x;
  float a = xr[t], b2 = xr[t + 256];
  float s = a + b2;
  #pragma unroll
  for (int o = 32; o; o >>= 1) s += __shfl_down(s, o, 64);
  if ((t & 63) == 0) red[t >> 6] = s;
  __syncthreads();
  float mu = (red[0] + red[1] + red[2] + red[3]) * (1.f / 512.f);
  __syncthreads();
  float c1 = a - mu, c2 = b2 - mu;
  float qq = c1 * c1 + c2 * c2;
  #pragma unroll
  for (int o = 32; o; o >>= 1) qq += __shfl_down(qq, o, 64);
  if ((t & 63) == 0) red[t >> 6] = qq;
  __syncthreads();
  float var = (red[0] + red[1] + red[2] + red[3]) * (1.f / 512.f);
  float rs = rsqrtf(var + 1e-5f);
  hb[row * 512 + t]       = (bf)(c1 * rs * sc[t] + bi[t]);
  hb[row * 512 + t + 256] = (bf)(c2 * rs * sc[t + 256] + bi[t + 256]);
}

// DELTAB = bf16(sum_z DP[z] + shifted AR terms)
__global__ void k_deltasS(const float* __restrict__ dp, long stride, int S,
                          const bf* __restrict__ callb, bf* __restrict__ db) {
  long id = (long)blockIdx.x * 256 + threadIdx.x;  // < 2097152
  int o = (int)(id & 511); long row = id >> 9; int tt = (int)(row & 1023);
  float v = 0.f;
  for (int zz = 0; zz < S; ++zz) v += dp[(long)zz * stride + id];
  for (int i = 0; i < 3; ++i)
    if (tt >= i) v += (float)callb[(row - i) * 1536 + i * 512 + o];
  db[id] = (bf)v;
}

// E[b*64+c][p] = sum_z YLOCp[z][b][c*16 + (p<512?15:14)][p&511] ; dual f32+bf16 out
__global__ void k_egather(const float* __restrict__ dp, long stride, int S,
                          float* __restrict__ E, bf* __restrict__ eb0) {
  long id = (long)blockIdx.x * 256 + threadIdx.x;  // < 262144
  int p = (int)(id & 1023); long r = id >> 10;
  int b = (int)(r >> 6), c = (int)(r & 63);
  int tq = c * 16 + ((p < 512) ? 15 : 14);
  long idx = ((long)(b << 10) + tq) * 512 + (p & 511);
  float v = 0.f;
  for (int zz = 0; zz < S; ++zz) v += dp[(long)zz * stride + idx];
  E[id] = v; eb0[id] = (bf)v;
}

__global__ void k_sfinal(const float* __restrict__ E, bf* __restrict__ ssb) {
  long id = (long)blockIdx.x * 256 + threadIdx.x;  // < 262144
  int c = (int)((id >> 10) & 63);
  ssb[id] = (c > 0) ? (bf)E[id - 1024] : (bf)0.f;
}

// y = sum_z YLOCp[z] + CM^{j+1}-row dot s ; out = bf16(gelu(y))
__global__ void k_combgelu(const float* __restrict__ dp, long stride, int S,
                           const bf* __restrict__ outh, bf* __restrict__ yg) {
  long id = (long)blockIdx.x * 256 + threadIdx.x;  // < 2097152
  int o = (int)(id & 511); long row = id >> 9;
  int b = (int)(row >> 10), tt = (int)(row & 1023);
  int c = tt >> 4, j = tt & 15;
  long wv = ((long)(j * 512 + o)) * 256 + b * 64 + c;
  float v = (float)outh[wv];
  for (int zz = 0; zz < S; ++zz) v += dp[(long)zz * stride + id];
  yg[id] = (bf)(0.5f * v * (1.f + erff(v * 0.70710678118654752f)));
}

__global__ void k_glures(const bf* __restrict__ g, float* __restrict__ x) {
  long id = (long)blockIdx.x * 256 + threadIdx.x;  // < 2097152
  int o = (int)(id & 511); long row = id >> 9;
  float a = (float)g[row * 1024 + o], bb = (float)g[row * 1024 + 512 + o];
  x[id] = x[id] + a / (1.f + expf(-bb));
}

__global__ void k_cast(const float* __restrict__ in, bf* __restrict__ out, long n4) {
  long id = (long)blockIdx.x * 256 + threadIdx.x;
  if (id >= n4) return;
  float4 v = *(const float4*)(in + id * 4);
  bfv4 o; o[0] = (bf)v.x; o[1] = (bf)v.y; o[2] = (bf)v.z; o[3] = (bf)v.w;
  *(bfv4*)(out + id * 4) = o;
}

__global__ void k_fill(float* p, long n, float v) {
  long id = (long)blockIdx.x * 256 + threadIdx.x;
  if (id < n) p[id] = v;
}

// ---------------- workspace layout (byte offsets) ----------------
struct Lay {
  long ZPG, SCL, EMBT, PROJT, TOEP, CMPOW, CMT2, WU, X, MPHITL, MUTL, W1TL,
       HB, HTB, DSLOT, DP, RC, E, EB0, EB1, SSTB, need;
  int nk, S, fullT;
};
static Lay mkLay(int nk, int S, int fullT) {
  Lay L; long o = 0;
  auto al = [&](long sz) { long r = o; o += (sz + 255) & ~255L; return r; };
  L.nk = nk; L.S = S; L.fullT = fullT;
  L.ZPG   = al(4096);
  L.SCL   = al(256);
  L.EMBT  = al(524288);
  L.PROJT = al(524288);
  L.TOEP  = al((long)(fullT ? 24 : nk) * 2097152);
  L.CMPOW = al(17L * 2097152);
  L.CMT2  = al(2L * 2097152);            // 2-slot ping-pong
  L.WU    = al(8388608);
  L.X     = al(8388608);
  L.MPHITL= al(12582912);
  L.MUTL  = al(1572864);
  L.W1TL  = al(1048576);
  L.HB    = al(4194304);
  L.HTB   = al(4194304);
  L.DSLOT = al(4194304);                 // DELTAB | YGB
  L.DP    = al((long)S * 8388608);       // f32 partials (phi, then yloc)
  long rc = (long)nk * 4194304;          // XTC
  if (rc < 16777216) rc = 16777216;      // CALLB(12.58M)+OUTH(4.19M); G(8.39M)
  L.RC    = al(rc);
  L.E     = al(1048576);
  L.EB0   = al(524288);
  L.EB1   = al(524288);
  L.SSTB  = al(524288);
  L.need  = o;
  return L;
}

extern "C" void kernel_launch(void* const* d_in, const int* in_sizes, int n_in,
                              void* d_out, int out_size, void* d_ws, size_t ws_size,
                              hipStream_t stream) {
  Lay L = mkLay(8, 4, 1);                         // ~206 MB
  if (L.need > (long)ws_size) L = mkLay(6, 4, 1); // ~197 MB
  if (L.need > (long)ws_size) L = mkLay(4, 4, 1); // ~189 MB
  if (L.need > (long)ws_size) L = mkLay(4, 2, 1); // ~172 MB (guaranteed: round-4 fit 178 MB)
  if (L.need > (long)ws_size) L = mkLay(4, 2, 0); // ~130 MB
  if (L.need > (long)ws_size) L = mkLay(2, 1, 0); // ~110 MB
  if (L.need > (long)ws_size) {                   // diagnostic: absmax ~= 1e6 + ws_MB
    k_fill<<<8192, 256, 0, stream>>>((float*)d_out, 2097152, 1.0e6f + (float)(ws_size >> 20));
    return;
  }
  const float* inp  = (const float*)d_in[0];
  const float* embw = (const float*)d_in[1];
  const float* embb = (const float*)d_in[2];
  const float* lns  = (const float*)d_in[3];
  const float* lnb  = (const float*)d_in[4];
  const float* m_y  = (const float*)d_in[5];
  const float* m_u  = (const float*)d_in[6];
  const float* mphi = (const float*)d_in[7];
  const float* w1   = (const float*)d_in[8];
  const float* b1   = (const float*)d_in[9];
  const float* pw   = (const float*)d_in[10];
  const float* pb   = (const float*)d_in[11];
  const float* evals = (const float*)d_in[12];
  const float* evecs = (const float*)d_in[13];

  char* w = (char*)d_ws;
  bf*    ZPG   = (bf*)(w + L.ZPG);
  float* SCL   = (float*)(w + L.SCL);
  bf*    EMBT  = (bf*)(w + L.EMBT);
  bf*    PROJT = (bf*)(w + L.PROJT);
  bf*    TOEP  = (bf*)(w + L.TOEP);
  bf*    CMPOW = (bf*)(w + L.CMPOW);
  bf*    CMT2a = (bf*)(w + L.CMT2);
  bf*    CMT2b = CMT2a + 1048576;
  bf*    WUa   = (bf*)(w + L.WU);                 // W | U pair (1M elems each)
  bf*    WUb   = (bf*)(w + L.WU + 4194304);
  float* X     = (float*)(w + L.X);
  bf*    MPHITL= (bf*)(w + L.MPHITL);
  bf*    MUTL  = (bf*)(w + L.MUTL);
  bf*    W1TL  = (bf*)(w + L.W1TL);
  bf*    HB    = (bf*)(w + L.HB);
  bf*    HTB   = (bf*)(w + L.HTB);
  bf*    DELTAB= (bf*)(w + L.DSLOT);
  bf*    YGB   = (bf*)(w + L.DSLOT);
  float* DP    = (float*)(w + L.DP);
  bf*    XTC   = (bf*)(w + L.RC);
  bf*    CALLB = (bf*)(w + L.RC);
  bf*    OUTH  = (bf*)(w + L.RC + 12582912);
  bf*    G     = (bf*)(w + L.RC);
  float* E     = (float*)(w + L.E);
  bf*    EB0   = (bf*)(w + L.EB0);
  bf*    EB1   = (bf*)(w + L.EB1);
  bf*    SSTB  = (bf*)(w + L.SSTB);
  bf*    INB   = HB;
  hipStream_t st = stream;
  const int nk = L.nk, S = L.S, nchunk = 24 / nk;
  const long DPS = 2097152;                       // DP z-stride in f32 elems
  const int Kcphi = nk * 512 / S, kzphi = Kcphi >> 9;
  const int Kcy = 8192 / S, kzy = Kcy >> 9;
  GOp gnull = {};

  hipMemsetAsync(w + L.ZPG, 0, 4096, st);

  // ---- one-time prep ----
  k_scl<<<1, 32, 0, st>>>(evals, SCL);
  k_trt<float, bf><<<dim3(8, 8, 1), 256, 0, st>>>(embw, EMBT, 512, 0, 512, 0);
  k_trt<float, bf><<<dim3(8, 8, 1), 256, 0, st>>>(pw, PROJT, 512, 0, 512, 0);
  if (L.fullT)
    k_toep<<<dim3((unsigned)((24L * 1048576) / 256)), 256, 0, st>>>(evecs, TOEP, 0, 24);
  k_cast<<<2048, 256, 0, st>>>(inp, INB, 524288);
  LG<1,1,0,0,0>(st, 32, 4, 1,
      mkop(INB, 512, 512, 262144, 0, 30, 0, EMBT, 512, 512, 0, 0, 0,
           X, 512, 0, nullptr, 0, 0, embb, 512, 0, 0), gnull, ZPG);

  for (int l = 0; l < 4; ++l) {
    // --- CM powers via merged dual-chain doubling (no transposes, 2-slot T ping-pong) ---
    k_buildCM<<<8192, 256, 0, st>>>(m_y + (long)l * 524288, CMPOW);
    k_trt<bf, bf><<<dim3(16, 16, 1), 256, 0, st>>>(CMPOW + 1048576, CMT2a, 1024, 0, 1024, 0);
    bf* curT = CMT2a;                    // holds (CM^{2^r})^T
    for (int r = 0; r < 4; ++r) {
      int s = 1 << r;
      bf* nxtT = (r & 1) ? CMT2a : CMT2b;
      GOp mn = mkop(CMPOW + 1048576, 1024, 512, 524288, 1048576, 0, 0,
                    curT, 1024, 512, 0, 0, 0,
                    nullptr, 0, 0, CMPOW + (long)(s + 1) * 1048576, 1024, 1048576,
                    nullptr, 1024, 0, 0);
      GOp sp = mkop(curT, 1024, 512, 524288, 0, 30, 0,
                    CMPOW + (long)s * 1048576, 1024, 512, 0, 0, 0,
                    nullptr, 0, 0, nxtT, 1024, 0,
                    nullptr, 1024, 0, 8);
      LG<0,0,1,0,0, 1, 0,0,1,0,0>(st, 8, 8, s + 1, mn, sp, ZPG);
      curT = nxtT;
    }
    // --- per-layer weight prep ---
    k_trtS<<<dim3(192, 8, 1), 256, 0, st>>>(mphi + (long)l * 6291456, MPHITL, 512, 12288, SCL);
    k_mut<<<3072, 256, 0, st>>>(m_u + (long)l * 786432, MUTL);
    k_trt<float, bf><<<dim3(8, 16, 1), 256, 0, st>>>(w1 + (long)l * 524288, W1TL, 1024, 0, 512, 0);

    // --- LN -> HB ; HTB per-batch transpose ---
    k_ln<<<4096, 256, 0, st>>>(X, lns + l * 512, lnb + l * 512, HB);
    k_trt<bf, bf><<<dim3(16, 8, 4), 256, 0, st>>>(HB, HTB, 512, 524288, 1024, 524288);

    // --- spectral: Toeplitz conv -> split-K phi projection into DP partials ---
    for (int kc = 0; kc < nchunk; ++kc) {
      const bf* tb = TOEP;
      if (L.fullT) tb = TOEP + (long)kc * nk * 1048576;
      else k_toep<<<dim3((unsigned)(((long)nk * 1048576) / 256)), 256, 0, st>>>(evecs, TOEP, kc * nk, nk);
      LG<0,0,1,0,0>(st, 8, 4, 4 * nk,
          mkop(tb, 1024, 512, 524288, 1048576, 2, 0,
               HTB, 1024, 512, 524288, 3, 0,
               nullptr, 0, 0, XTC, 512, 524288, nullptr, 1024, 0, 0), gnull, ZPG);
      GOp pg = mkop(XTC, 512, 2097152, 262144, 0, 30, kzphi,
                    MPHITL + (long)kc * nk * 512, 12288, 512, 0, 0, kzphi,
                    DP, 512, DPS, nullptr, 0, 0, nullptr, Kcphi, 0, 0);
      if (kc == 0) LG<0,1,0,0,0>(st, 32, 4, S, pg, gnull, ZPG);
      else         LG<0,1,0,0,1>(st, 32, 4, S, pg, gnull, ZPG);
    }

    // --- AR terms + deltas (sums DP partials) ---
    LG<0,0,1,0,0>(st, 32, 12, 1,
        mkop(HB, 512, 512, 262144, 0, 30, 0, MUTL, 512, 512, 0, 0, 0,
             nullptr, 0, 0, CALLB, 1536, 0, nullptr, 512, 0, 0), gnull, ZPG);
    k_deltasS<<<8192, 256, 0, st>>>(DP, DPS, S, CALLB, DELTAB);

    // --- local solutions: causal im2col x CM-power blocks, split-K into DP ---
    LG<0,1,0,1,0>(st, 32, 4, S,
        mkop(DELTAB, 512, -512, 262144, 0, 30, kzy,
             CMPOW, 1024, 1048576, 0, 0, kzy,
             DP, 512, DPS, nullptr, 0, 0, nullptr, Kcy, 0, 0), gnull, ZPG);

    // --- Kogge-Stone chunk-state scan: merged {W/U squaring | E-update} ---
    k_egather<<<1024, 256, 0, st>>>(DP, DPS, S, E, EB0);
    const bf* Wc = CMPOW + 16L * 1048576;         // W^1 = T = CM^16
    const bf* Uc = curT;                          // U^1 = (CM^16)^T
    bf* EBc = EB0; bf* EBn = EB1;
    bf* WUn = WUa;
    for (int k = 1; k <= 5; ++k) {
      int sh = 1 << (k - 1);
      GOp mn = mkop(Wc, 1024, 512, 524288, (long)(Uc - Wc), 0, 0,
                    Uc, 1024, 512, (long)(Wc - Uc), 1, 0,
                    nullptr, 0, 0, WUn, 1024, 1048576, nullptr, 1024, 0, 0);
      GOp sp = mkop(EBc - (long)sh * 1024, 1024, 512, 524288, 0, 30, 0,
                    Wc, 1024, 512, 0, 0, 0,
                    E, 1024, 0, EBn, 1024, 0, nullptr, 1024, sh, 2);
      LG<0,0,1,0,0, 1, 0,1,1,2,1>(st, 8, 8, 3, mn, sp, ZPG);
      Wc = WUn; Uc = WUn + 1048576;
      WUn = (k & 1) ? WUb : WUa;
      bf* tmp = EBc; EBc = EBn; EBn = tmp;
    }
    LG<0,1,0,2,1>(st, 2, 8, 1,
        mkop(EBc - 32L * 1024, 1024, 512, 524288, 0, 30, 0,
             Wc, 1024, 512, 0, 0, 0,
             E, 1024, 0, nullptr, 0, 0, nullptr, 1024, 32, 0), gnull, ZPG);
    k_sfinal<<<1024, 256, 0, st>>>(E, SSTB);

    // --- homogeneous completion + gelu + MLP(GLU) + residual ---
    LG<0,0,1,0,0>(st, 64, 2, 1,
        mkop(CMPOW + 1048576, 1024, 512, 1048576, 0, 30, 0,
             SSTB, 1024, 512, 0, 0, 0,
             nullptr, 0, 0, OUTH, 256, 0, nullptr, 1024, 0, 0), gnull, ZPG);
    k_combgelu<<<8192, 256, 0, st>>>(DP, DPS, S, OUTH, YGB);
    LG<1,0,1,0,0>(st, 32, 8, 1,
        mkop(YGB, 512, 512, 262144, 0, 30, 0, W1TL, 512, 512, 0, 0, 0,
             nullptr, 0, 0, G, 1024, 0, b1 + (long)l * 1024, 512, 0, 0), gnull, ZPG);
    k_glures<<<8192, 256, 0, st>>>(G, X);
  }

  // ---- output projection ----
  k_cast<<<2048, 256, 0, st>>>(X, INB, 524288);
  LG<1,1,0,0,0>(st, 32, 4, 1,
      mkop(INB, 512, 512, 262144, 0, 30, 0, PROJT, 512, 512, 0, 0, 0,
           (float*)d_out, 512, 0, nullptr, 0, 0, pb, 512, 0, 0), gnull, ZPG);
}

// Round 6
// 3135.660 us; speedup vs baseline: 4.2699x; 1.0999x over previous
//
#include <hip/hip_runtime.h>
#include <math.h>

typedef __bf16 bf;
typedef __attribute__((ext_vector_type(4))) __bf16 bfv4;
typedef __attribute__((ext_vector_type(8))) __bf16 bfv8;
typedef __attribute__((ext_vector_type(4))) float f32x4;

__device__ __forceinline__ void gload16(const void* g, void* l) {
  __builtin_amdgcn_global_load_lds((const __attribute__((address_space(1))) void*)g,
                                   (__attribute__((address_space(3))) void*)l, 16, 0, 0);
}

// ---------------- generalized GEMM op descriptor ----------------
// C[M,N] = A[M,K] * Bt[N,K]^T, bf16 in, f32 accum, 128x128 tile, BK=32.
// A row addr: (row>>9)*lMa + (row&511)*la ; K addr: blk*lK + (k&511),
// blk = (k>>9) + z*kz (absolute block for split-K). Z: A += (z>>zshA)*sAz,
// B += (z&zmskB)*sBz, C/Cb += z*s{C,Cb}z.
// tMASK=1: causal im2col (valid iff (row&15) >= blk), zero-page redirect.
// tMASK=2: scan shift (valid iff (row&63) >= maskCmp), zero-page redirect.
// tMASK=3: Toeplitz conv: A elem(row=t, k=s) = pvec[c*2065 + 1023 - t + s],
//          c=(t+1)&7 (8 shifted copies for 16B alignment; zero-pad = causality).
struct GOp {
  const bf* A; long la, lKa, lMa, sAz; int zshA, kzA;
  const bf* B; long lb, lKb, sBz; int zmskB, kzB;
  float* C; long ldc, sCz;
  bf* Cb; long ldcb, sCbz;
  const float* bias; int K, maskCmp, mBlk;
};

template<int tB,int tF32,int tB16,int tMASK,int tACC>
__device__ __forceinline__ void gbody(const GOp g, int z, bf* lsA, bf* lsB, const bf* zpg) {
  const int t = threadIdx.x;
  const long m0 = (long)blockIdx.x * 128, n0 = (long)blockIdx.y * 128;
  const bf* Ap = g.A + (long)(z >> g.zshA) * g.sAz;
  const bf* Bp = g.B + (long)(z & g.zmskB) * g.sBz;
  const int w = t >> 6, l = t & 63;
  const int wm = (w >> 1) * 64, wn = (w & 1) * 64;
  const int lr = l & 15, lk = (l >> 4) * 8;
  const int r0 = t >> 2, ko = (t & 3) * 8;
  const long rowA1 = m0 + r0, rowA2 = rowA1 + 64;
  const long baseA1 = (rowA1 >> 9) * g.lMa + (rowA1 & 511) * g.la;
  const long baseA2 = (rowA2 >> 9) * g.lMa + (rowA2 & 511) * g.la;
  const long baseB1 = (n0 + r0) * g.lb;
  const int zbA = z * g.kzA, zbB = z * g.kzB;
  // conv-mode base: copies stride 2064, +c for shift; (t+1)&7 alignment copy
  const int ct = ((int)rowA1 + 1) & 7;
  const long convB = (long)ct * 2065 + 1023 - (long)rowA1;
  f32x4 acc[4][4];
  #pragma unroll
  for (int i = 0; i < 4; i++)
    #pragma unroll
    for (int j = 0; j < 4; j++) acc[i][j] = (f32x4){0.f, 0.f, 0.f, 0.f};

  for (int k0 = 0; k0 < g.K; k0 += 32) {
    const int kk = k0 + ko;
    const int bA = (kk >> 9) + zbA, bB = (kk >> 9) + zbB;
    const long kb = (long)bB * g.lKb + (kk & 511);
    const bf* ga; const bf* ga2;
    if (tMASK == 3) {
      ga  = Ap + convB + kk;
      ga2 = ga - 64;
    } else {
      const long ka = (long)bA * g.lKa + (kk & 511);
      ga  = Ap + baseA1 + ka;
      ga2 = Ap + baseA2 + ka;
      if (tMASK == 1) { if ((int)(rowA1 & 15) < bA) { ga = zpg; ga2 = zpg; } }
      if (tMASK == 2) { if ((int)(rowA1 & 63) < g.maskCmp) { ga = zpg; ga2 = zpg; } }
    }
    const bf* gb = Bp + baseB1 + kb;
    gload16(ga,            &lsA[t * 8]);
    gload16(ga2,           &lsA[2048 + t * 8]);
    gload16(gb,            &lsB[t * 8]);
    gload16(gb + 64 * g.lb, &lsB[2048 + t * 8]);
    __syncthreads();
    bfv8 av[4], bv[4];
    #pragma unroll
    for (int i = 0; i < 4; i++) av[i] = *(const bfv8*)&lsA[(wm + i * 16 + lr) * 32 + lk];
    #pragma unroll
    for (int i = 0; i < 4; i++) bv[i] = *(const bfv8*)&lsB[(wn + i * 16 + lr) * 32 + lk];
    #pragma unroll
    for (int i = 0; i < 4; i++)
      #pragma unroll
      for (int j = 0; j < 4; j++)
        acc[i][j] = __builtin_amdgcn_mfma_f32_16x16x32_bf16(av[i], bv[j], acc[i][j], 0, 0, 0);
    __syncthreads();
  }
  const int orow = (l >> 4) * 4, ocol = lr;
  #pragma unroll
  for (int i = 0; i < 4; i++)
    #pragma unroll
    for (int j = 0; j < 4; j++) {
      long col = n0 + wn + j * 16 + ocol;
      float bb = tB ? g.bias[col] : 0.f;
      #pragma unroll
      for (int r = 0; r < 4; r++) {
        long row = m0 + wm + i * 16 + orow + r;
        float v = acc[i][j][r] + bb;
        if (tF32) {
          long idx = (long)z * g.sCz + row * g.ldc + col;
          if (tACC) v += g.C[idx];
          g.C[idx] = v;
        }
        if (tB16) g.Cb[(long)z * g.sCbz + row * g.ldcb + col] = (bf)v;
      }
    }
}

// merged kernel: z < gridDim.z-1 (or tSPEC=0): main op; last z: special op.
template<int tB,int tF32,int tB16,int tMASK,int tACC,int tSPEC,
         int sB,int sF32,int sB16,int sMASK,int sACC>
__global__ __launch_bounds__(256) void gemm_k(GOp g, GOp gx, const bf* __restrict__ zpg) {
  __shared__ bf lsA[4096], lsB[4096];
  int z = blockIdx.z;
  if (tSPEC && z == (int)gridDim.z - 1) {
    if ((int)blockIdx.x >= gx.mBlk) return;
    gbody<sB,sF32,sB16,sMASK,sACC>(gx, 0, lsA, lsB, zpg);
  } else {
    gbody<tB,tF32,tB16,tMASK,tACC>(g, z, lsA, lsB, zpg);
  }
}

static inline GOp mkop(const void* A, long la, long lKa, long lMa, long sAz, int zshA, int kzA,
                       const void* B, long lb, long lKb, long sBz, int zmskB, int kzB,
                       void* C, long ldc, long sCz, void* Cb, long ldcb, long sCbz,
                       const void* bias, int K, int maskCmp, int mBlk) {
  GOp g;
  g.A = (const bf*)A; g.la = la; g.lKa = lKa; g.lMa = lMa; g.sAz = sAz; g.zshA = zshA; g.kzA = kzA;
  g.B = (const bf*)B; g.lb = lb; g.lKb = lKb; g.sBz = sBz; g.zmskB = zmskB; g.kzB = kzB;
  g.C = (float*)C; g.ldc = ldc; g.sCz = sCz;
  g.Cb = (bf*)Cb; g.ldcb = ldcb; g.sCbz = sCbz;
  g.bias = (const float*)bias; g.K = K; g.maskCmp = maskCmp; g.mBlk = mBlk;
  return g;
}

template<int tB,int tF32,int tB16,int tMASK,int tACC,int tSPEC=0,
         int sB=0,int sF32=0,int sB16=0,int sMASK=0,int sACC=0>
static inline void LG(hipStream_t st, int gx, int gy, int gz, const GOp& g, const GOp& gs, const bf* zpg) {
  gemm_k<tB,tF32,tB16,tMASK,tACC,tSPEC,sB,sF32,sB16,sMASK,sACC>
      <<<dim3(gx, gy, gz), 256, 0, st>>>(g, gs, zpg);
}

// ---------------- small kernels ----------------

template<typename TI, typename TO>
__global__ __launch_bounds__(256) void k_trt(const TI* __restrict__ in, TO* __restrict__ out,
                                             long ldin, long inz, long ldout, long outz) {
  __shared__ float tile[64][65];
  int z = blockIdx.z;
  int c0 = blockIdx.x * 64, r0 = blockIdx.y * 64;
  int tx = threadIdx.x & 63, ty = threadIdx.x >> 6;
  #pragma unroll
  for (int i = ty; i < 64; i += 4) tile[i][tx] = (float)in[(long)z * inz + (long)(c0 + i) * ldin + r0 + tx];
  __syncthreads();
  #pragma unroll
  for (int i = ty; i < 64; i += 4) out[(long)z * outz + (long)(r0 + i) * ldout + c0 + tx] = (TO)tile[tx][i];
}

// scaled transpose-cast (for m_phi^T): out[r][c] = bf16(in[c][r] * scl[c>>9])
__global__ __launch_bounds__(256) void k_trtS(const float* __restrict__ in, bf* __restrict__ out,
                                              long ldin, long ldout, const float* __restrict__ scl) {
  __shared__ float tile[64][65];
  int c0 = blockIdx.x * 64, r0 = blockIdx.y * 64;
  int tx = threadIdx.x & 63, ty = threadIdx.x >> 6;
  #pragma unroll
  for (int i = ty; i < 64; i += 4) tile[i][tx] = in[(long)(c0 + i) * ldin + r0 + tx];
  __syncthreads();
  float sc = scl[(c0 + tx) >> 9];
  #pragma unroll
  for (int i = ty; i < 64; i += 4) out[(long)(r0 + i) * ldout + c0 + tx] = (bf)(tile[tx][i] * sc);
}

__global__ void k_scl(const float* __restrict__ evals, float* __restrict__ scl) {
  int k = threadIdx.x;
  if (k < 24) scl[k] = powf(evals[k], 0.25f);
}

// padded reversed eigvec copies: pvec[k][c][j] = (0<=j-c<=1023)? evec[1023-(j-c)][k] : 0
// copy stride 2064 elems, per-filter 16512 elems.
__global__ void k_pvec(const float* __restrict__ evecs, bf* __restrict__ out) {
  long id = (long)blockIdx.x * 256 + threadIdx.x;
  if (id >= 24L * 16512) return;
  int kf = (int)(id / 16512);
  int rem = (int)(id % 16512);
  int c = rem / 2064, j = rem % 2064;
  int d = j - c;
  float v = (d >= 0 && d <= 1023) ? evecs[(long)(1023 - d) * 24 + kf] : 0.f;
  out[id] = (bf)v;
}

__global__ void k_mut(const float* __restrict__ mul_, bf* __restrict__ out) {
  long id = (long)blockIdx.x * 256 + threadIdx.x;  // < 786432
  long r = id >> 9; int d = (int)(id & 511);
  int i = (int)(r >> 9), o = (int)(r & 511);
  out[id] = (bf)mul_[(long)o * 1536 + d * 3 + i];
}

// CMPOW[0] = I(1024), CMPOW[1] = [[A,B],[I,0]]
__global__ void k_buildCM(const float* __restrict__ myl, bf* __restrict__ cmpow) {
  long id = (long)blockIdx.x * 256 + threadIdx.x;  // < 2097152
  int half = (int)(id >> 20);
  int r = (int)(id & 1048575);
  int p = r >> 10, q = r & 1023;
  float v;
  if (half == 0) v = (p == q) ? 1.f : 0.f;
  else if (p < 512) v = myl[(long)p * 1024 + q];
  else v = (q == p - 512) ? 1.f : 0.f;
  cmpow[id] = (bf)v;
}

__global__ __launch_bounds__(256) void k_ln(const float* __restrict__ x, const float* __restrict__ sc,
                                            const float* __restrict__ bi, bf* __restrict__ hb) {
  __shared__ float red[8];
  long row = blockIdx.x;
  const float* xr = x + row * 512;
  int t = threadIdx.x;
  float a = xr[t], b2 = xr[t + 256];
  float s = a + b2;
  #pragma unroll
  for (int o = 32; o; o >>= 1) s += __shfl_down(s, o, 64);
  if ((t & 63) == 0) red[t >> 6] = s;
  __syncthreads();
  float mu = (red[0] + red[1] + red[2] + red[3]) * (1.f / 512.f);
  __syncthreads();
  float c1 = a - mu, c2 = b2 - mu;
  float qq = c1 * c1 + c2 * c2;
  #pragma unroll
  for (int o = 32; o; o >>= 1) qq += __shfl_down(qq, o, 64);
  if ((t & 63) == 0) red[t >> 6] = qq;
  __syncthreads();
  float var = (red[0] + red[1] + red[2] + red[3]) * (1.f / 512.f);
  float rs = rsqrtf(var + 1e-5f);
  hb[row * 512 + t]       = (bf)(c1 * rs * sc[t] + bi[t]);
  hb[row * 512 + t + 256] = (bf)(c2 * rs * sc[t + 256] + bi[t + 256]);
}

// DELTAB = bf16(sum_z DP[z] + shifted AR terms)
__global__ void k_deltasS(const float* __restrict__ dp, long stride, int S,
                          const bf* __restrict__ callb, bf* __restrict__ db) {
  long id = (long)blockIdx.x * 256 + threadIdx.x;  // < 2097152
  int o = (int)(id & 511); long row = id >> 9; int tt = (int)(row & 1023);
  float v = 0.f;
  for (int zz = 0; zz < S; ++zz) v += dp[(long)zz * stride + id];
  for (int i = 0; i < 3; ++i)
    if (tt >= i) v += (float)callb[(row - i) * 1536 + i * 512 + o];
  db[id] = (bf)v;
}

// E[b*64+c][p] = sum_z YLOCp[z][b][c*16 + (p<512?15:14)][p&511] ; dual f32+bf16 out
__global__ void k_egather(const float* __restrict__ dp, long stride, int S,
                          float* __restrict__ E, bf* __restrict__ eb0) {
  long id = (long)blockIdx.x * 256 + threadIdx.x;  // < 262144
  int p = (int)(id & 1023); long r = id >> 10;
  int b = (int)(r >> 6), c = (int)(r & 63);
  int tq = c * 16 + ((p < 512) ? 15 : 14);
  long idx = ((long)(b << 10) + tq) * 512 + (p & 511);
  float v = 0.f;
  for (int zz = 0; zz < S; ++zz) v += dp[(long)zz * stride + idx];
  E[id] = v; eb0[id] = (bf)v;
}

__global__ void k_sfinal(const float* __restrict__ E, bf* __restrict__ ssb) {
  long id = (long)blockIdx.x * 256 + threadIdx.x;  // < 262144
  int c = (int)((id >> 10) & 63);
  ssb[id] = (c > 0) ? (bf)E[id - 1024] : (bf)0.f;
}

// y = sum_z YLOCp[z] + CM^{j+1}-row dot s ; out = bf16(gelu(y))
__global__ void k_combgelu(const float* __restrict__ dp, long stride, int S,
                           const bf* __restrict__ outh, bf* __restrict__ yg) {
  long id = (long)blockIdx.x * 256 + threadIdx.x;  // < 2097152
  int o = (int)(id & 511); long row = id >> 9;
  int b = (int)(row >> 10), tt = (int)(row & 1023);
  int c = tt >> 4, j = tt & 15;
  long wv = ((long)(j * 512 + o)) * 256 + b * 64 + c;
  float v = (float)outh[wv];
  for (int zz = 0; zz < S; ++zz) v += dp[(long)zz * stride + id];
  yg[id] = (bf)(0.5f * v * (1.f + erff(v * 0.70710678118654752f)));
}

__global__ void k_glures(const bf* __restrict__ g, float* __restrict__ x) {
  long id = (long)blockIdx.x * 256 + threadIdx.x;  // < 2097152
  int o = (int)(id & 511); long row = id >> 9;
  float a = (float)g[row * 1024 + o], bb = (float)g[row * 1024 + 512 + o];
  x[id] = x[id] + a / (1.f + expf(-bb));
}

__global__ void k_cast(const float* __restrict__ in, bf* __restrict__ out, long n4) {
  long id = (long)blockIdx.x * 256 + threadIdx.x;
  if (id >= n4) return;
  float4 v = *(const float4*)(in + id * 4);
  bfv4 o; o[0] = (bf)v.x; o[1] = (bf)v.y; o[2] = (bf)v.z; o[3] = (bf)v.w;
  *(bfv4*)(out + id * 4) = o;
}

__global__ void k_fill(float* p, long n, float v) {
  long id = (long)blockIdx.x * 256 + threadIdx.x;
  if (id < n) p[id] = v;
}

// ---------------- workspace layout (byte offsets) ----------------
struct Lay {
  long ZPG, SCL, EMBT, PROJT, PVEC, CMPOW, CMT2, WU, X, MPHITL, MUTL, W1TL,
       HB, HTB, DSLOT, DP, RC, E, EB0, EB1, SSTB, need;
  int nk, S;
};
static Lay mkLay(int nk, int S) {
  Lay L; long o = 0;
  auto al = [&](long sz) { long r = o; o += (sz + 255) & ~255L; return r; };
  L.nk = nk; L.S = S;
  L.ZPG   = al(4096);
  L.SCL   = al(256);
  L.EMBT  = al(524288);
  L.PROJT = al(524288);
  L.PVEC  = al(24L * 16512 * 2);
  L.CMPOW = al(17L * 2097152);
  L.CMT2  = al(2L * 2097152);            // 2-slot ping-pong
  L.WU    = al(8388608);
  L.X     = al(8388608);
  L.MPHITL= al(12582912);
  L.MUTL  = al(1572864);
  L.W1TL  = al(1048576);
  L.HB    = al(4194304);
  L.HTB   = al(4194304);
  L.DSLOT = al(4194304);                 // DELTAB | YGB
  L.DP    = al((long)S * 8388608);       // f32 partials (phi, then yloc)
  long rc = (long)nk * 4194304;          // XTC
  if (rc < 16777216) rc = 16777216;      // CALLB(12.58M)+OUTH(4.19M); G(8.39M)
  L.RC    = al(rc);
  L.E     = al(1048576);
  L.EB0   = al(524288);
  L.EB1   = al(524288);
  L.SSTB  = al(524288);
  L.need  = o;
  return L;
}

extern "C" void kernel_launch(void* const* d_in, const int* in_sizes, int n_in,
                              void* d_out, int out_size, void* d_ws, size_t ws_size,
                              hipStream_t stream) {
  Lay L = mkLay(12, 4);                        // ~165 MB (proven floor: >=170 MB available)
  if (L.need > (long)ws_size) L = mkLay(8, 4); // ~149 MB
  if (L.need > (long)ws_size) L = mkLay(4, 2); // ~116 MB
  if (L.need > (long)ws_size) {                // diagnostic: absmax ~= 1e6 + ws_MB
    k_fill<<<8192, 256, 0, stream>>>((float*)d_out, 2097152, 1.0e6f + (float)(ws_size >> 20));
    return;
  }
  const float* inp  = (const float*)d_in[0];
  const float* embw = (const float*)d_in[1];
  const float* embb = (const float*)d_in[2];
  const float* lns  = (const float*)d_in[3];
  const float* lnb  = (const float*)d_in[4];
  const float* m_y  = (const float*)d_in[5];
  const float* m_u  = (const float*)d_in[6];
  const float* mphi = (const float*)d_in[7];
  const float* w1   = (const float*)d_in[8];
  const float* b1   = (const float*)d_in[9];
  const float* pw   = (const float*)d_in[10];
  const float* pb   = (const float*)d_in[11];
  const float* evals = (const float*)d_in[12];
  const float* evecs = (const float*)d_in[13];

  char* w = (char*)d_ws;
  bf*    ZPG   = (bf*)(w + L.ZPG);
  float* SCL   = (float*)(w + L.SCL);
  bf*    EMBT  = (bf*)(w + L.EMBT);
  bf*    PROJT = (bf*)(w + L.PROJT);
  bf*    PVEC  = (bf*)(w + L.PVEC);
  bf*    CMPOW = (bf*)(w + L.CMPOW);
  bf*    CMT2a = (bf*)(w + L.CMT2);
  bf*    CMT2b = CMT2a + 1048576;
  bf*    WUa   = (bf*)(w + L.WU);                 // W | U pair (1M elems each)
  bf*    WUb   = (bf*)(w + L.WU + 4194304);
  float* X     = (float*)(w + L.X);
  bf*    MPHITL= (bf*)(w + L.MPHITL);
  bf*    MUTL  = (bf*)(w + L.MUTL);
  bf*    W1TL  = (bf*)(w + L.W1TL);
  bf*    HB    = (bf*)(w + L.HB);
  bf*    HTB   = (bf*)(w + L.HTB);
  bf*    DELTAB= (bf*)(w + L.DSLOT);
  bf*    YGB   = (bf*)(w + L.DSLOT);
  float* DP    = (float*)(w + L.DP);
  bf*    XTC   = (bf*)(w + L.RC);
  bf*    CALLB = (bf*)(w + L.RC);
  bf*    OUTH  = (bf*)(w + L.RC + 12582912);
  bf*    G     = (bf*)(w + L.RC);
  float* E     = (float*)(w + L.E);
  bf*    EB0   = (bf*)(w + L.EB0);
  bf*    EB1   = (bf*)(w + L.EB1);
  bf*    SSTB  = (bf*)(w + L.SSTB);
  bf*    INB   = HB;
  hipStream_t st = stream;
  const int nk = L.nk, S = L.S, nchunk = 24 / nk;
  const long DPS = 2097152;                       // DP z-stride in f32 elems
  const int Kcphi = nk * 512 / S, kzphi = Kcphi >> 9;
  const int Kcy = 8192 / S, kzy = Kcy >> 9;
  GOp gnull = {};

  hipMemsetAsync(w + L.ZPG, 0, 4096, st);

  // ---- one-time prep ----
  k_scl<<<1, 32, 0, st>>>(evals, SCL);
  k_pvec<<<1549, 256, 0, st>>>(evecs, PVEC);
  k_trt<float, bf><<<dim3(8, 8, 1), 256, 0, st>>>(embw, EMBT, 512, 0, 512, 0);
  k_trt<float, bf><<<dim3(8, 8, 1), 256, 0, st>>>(pw, PROJT, 512, 0, 512, 0);
  k_cast<<<2048, 256, 0, st>>>(inp, INB, 524288);
  LG<1,1,0,0,0>(st, 32, 4, 1,
      mkop(INB, 512, 512, 262144, 0, 30, 0, EMBT, 512, 512, 0, 0, 0,
           X, 512, 0, nullptr, 0, 0, embb, 512, 0, 0), gnull, ZPG);

  for (int l = 0; l < 4; ++l) {
    // --- CM powers via merged dual-chain doubling (no transposes, 2-slot T ping-pong) ---
    k_buildCM<<<8192, 256, 0, st>>>(m_y + (long)l * 524288, CMPOW);
    k_trt<bf, bf><<<dim3(16, 16, 1), 256, 0, st>>>(CMPOW + 1048576, CMT2a, 1024, 0, 1024, 0);
    bf* curT = CMT2a;                    // holds (CM^{2^r})^T
    for (int r = 0; r < 4; ++r) {
      int s = 1 << r;
      bf* nxtT = (r & 1) ? CMT2a : CMT2b;
      GOp mn = mkop(CMPOW + 1048576, 1024, 512, 524288, 1048576, 0, 0,
                    curT, 1024, 512, 0, 0, 0,
                    nullptr, 0, 0, CMPOW + (long)(s + 1) * 1048576, 1024, 1048576,
                    nullptr, 1024, 0, 0);
      GOp sp = mkop(curT, 1024, 512, 524288, 0, 30, 0,
                    CMPOW + (long)s * 1048576, 1024, 512, 0, 0, 0,
                    nullptr, 0, 0, nxtT, 1024, 0,
                    nullptr, 1024, 0, 8);
      LG<0,0,1,0,0, 1, 0,0,1,0,0>(st, 8, 8, s + 1, mn, sp, ZPG);
      curT = nxtT;
    }
    // --- per-layer weight prep ---
    k_trtS<<<dim3(192, 8, 1), 256, 0, st>>>(mphi + (long)l * 6291456, MPHITL, 512, 12288, SCL);
    k_mut<<<3072, 256, 0, st>>>(m_u + (long)l * 786432, MUTL);
    k_trt<float, bf><<<dim3(8, 16, 1), 256, 0, st>>>(w1 + (long)l * 524288, W1TL, 1024, 0, 512, 0);

    // --- LN -> HB ; HTB per-batch transpose ---
    k_ln<<<4096, 256, 0, st>>>(X, lns + l * 512, lnb + l * 512, HB);
    k_trt<bf, bf><<<dim3(16, 8, 4), 256, 0, st>>>(HB, HTB, 512, 524288, 1024, 524288);

    // --- spectral: direct Toeplitz conv (padded-vector A) -> split-K phi proj ---
    for (int kc = 0; kc < nchunk; ++kc) {
      LG<0,0,1,3,0>(st, 8, 4, 4 * nk,
          mkop(PVEC + (long)kc * nk * 16512, 0, 0, 0, 16512, 2, 0,
               HTB, 1024, 512, 524288, 3, 0,
               nullptr, 0, 0, XTC, 512, 524288, nullptr, 1024, 0, 0), gnull, ZPG);
      GOp pg = mkop(XTC, 512, 2097152, 262144, 0, 30, kzphi,
                    MPHITL + (long)kc * nk * 512, 12288, 512, 0, 0, kzphi,
                    DP, 512, DPS, nullptr, 0, 0, nullptr, Kcphi, 0, 0);
      if (kc == 0) LG<0,1,0,0,0>(st, 32, 4, S, pg, gnull, ZPG);
      else         LG<0,1,0,0,1>(st, 32, 4, S, pg, gnull, ZPG);
    }

    // --- AR terms + deltas (sums DP partials) ---
    LG<0,0,1,0,0>(st, 32, 12, 1,
        mkop(HB, 512, 512, 262144, 0, 30, 0, MUTL, 512, 512, 0, 0, 0,
             nullptr, 0, 0, CALLB, 1536, 0, nullptr, 512, 0, 0), gnull, ZPG);
    k_deltasS<<<8192, 256, 0, st>>>(DP, DPS, S, CALLB, DELTAB);

    // --- local solutions: causal im2col x CM-power blocks, split-K into DP ---
    LG<0,1,0,1,0>(st, 32, 4, S,
        mkop(DELTAB, 512, -512, 262144, 0, 30, kzy,
             CMPOW, 1024, 1048576, 0, 0, kzy,
             DP, 512, DPS, nullptr, 0, 0, nullptr, Kcy, 0, 0), gnull, ZPG);

    // --- Kogge-Stone chunk-state scan: merged {W/U squaring | E-update} ---
    k_egather<<<1024, 256, 0, st>>>(DP, DPS, S, E, EB0);
    const bf* Wc = CMPOW + 16L * 1048576;         // W^1 = T = CM^16
    const bf* Uc = curT;                          // U^1 = (CM^16)^T
    bf* EBc = EB0; bf* EBn = EB1;
    bf* WUn = WUa;
    for (int k = 1; k <= 5; ++k) {
      int sh = 1 << (k - 1);
      GOp mn = mkop(Wc, 1024, 512, 524288, (long)(Uc - Wc), 0, 0,
                    Uc, 1024, 512, (long)(Wc - Uc), 1, 0,
                    nullptr, 0, 0, WUn, 1024, 1048576, nullptr, 1024, 0, 0);
      GOp sp = mkop(EBc - (long)sh * 1024, 1024, 512, 524288, 0, 30, 0,
                    Wc, 1024, 512, 0, 0, 0,
                    E, 1024, 0, EBn, 1024, 0, nullptr, 1024, sh, 2);
      LG<0,0,1,0,0, 1, 0,1,1,2,1>(st, 8, 8, 3, mn, sp, ZPG);
      Wc = WUn; Uc = WUn + 1048576;
      WUn = (k & 1) ? WUb : WUa;
      bf* tmp = EBc; EBc = EBn; EBn = tmp;
    }
    LG<0,1,0,2,1>(st, 2, 8, 1,
        mkop(EBc - 32L * 1024, 1024, 512, 524288, 0, 30, 0,
             Wc, 1024, 512, 0, 0, 0,
             E, 1024, 0, nullptr, 0, 0, nullptr, 1024, 32, 0), gnull, ZPG);
    k_sfinal<<<1024, 256, 0, st>>>(E, SSTB);

    // --- homogeneous completion + gelu + MLP(GLU) + residual ---
    LG<0,0,1,0,0>(st, 64, 2, 1,
        mkop(CMPOW + 1048576, 1024, 512, 1048576, 0, 30, 0,
             SSTB, 1024, 512, 0, 0, 0,
             nullptr, 0, 0, OUTH, 256, 0, nullptr, 1024, 0, 0), gnull, ZPG);
    k_combgelu<<<8192, 256, 0, st>>>(DP, DPS, S, OUTH, YGB);
    LG<1,0,1,0,0>(st, 32, 8, 1,
        mkop(YGB, 512, 512, 262144, 0, 30, 0, W1TL, 512, 512, 0, 0, 0,
             nullptr, 0, 0, G, 1024, 0, b1 + (long)l * 1024, 512, 0, 0), gnull, ZPG);
    k_glures<<<8192, 256, 0, st>>>(G, X);
  }

  // ---- output projection ----
  k_cast<<<2048, 256, 0, st>>>(X, INB, 524288);
  LG<1,1,0,0,0>(st, 32, 4, 1,
      mkop(INB, 512, 512, 262144, 0, 30, 0, PROJT, 512, 512, 0, 0, 0,
           (float*)d_out, 512, 0, nullptr, 0, 0, pb, 512, 0, 0), gnull, ZPG);
}